// Round 4
// baseline (13341.777 us; speedup 1.0000x reference)
//
#include <hip/hip_runtime.h>

typedef unsigned short u16;
typedef unsigned int   u32;
typedef __attribute__((ext_vector_type(8))) short bh8;
typedef __attribute__((ext_vector_type(4))) float f4;

constexpr int BATCH = 8, HIDN = 1024, NHEAD = 8, HD = 256, NLAY = 18, DMLP = 4096;
constexpr int AHOR = 50, ADIMN = 32, PFXN = 1037, SEQN = 1087, NSTR = 17, MR = 400, MP = 512;
constexpr float EPSV = 1e-6f, NEGV = -2.3819763e38f, QSCALE = 0.0625f;
constexpr int NBLK = 256;
constexpr size_t ADASL = (size_t)37 * 3 * BATCH * HIDN; // 909312

static __device__ __forceinline__ u16 f2bf(float x){
  union{float f; u32 u;} v; v.f = x;
  u32 r = (v.u + 0x7FFFu + ((v.u >> 16) & 1u)) >> 16;
  return (u16)r;
}
static __device__ __forceinline__ float bf2f(u16 u){
  union{u32 u; float f;} v; v.u = ((u32)u) << 16; return v.f;
}
static __device__ __forceinline__ u32 pack2(float a, float b){
  return (u32)f2bf(a) | ((u32)f2bf(b) << 16);
}
static __device__ __forceinline__ f4 MFMA(bh8 a, bh8 b, f4 c){
  return __builtin_amdgcn_mfma_f32_16x16x32_bf16(a, b, c, 0, 0, 0);
}
static __device__ __forceinline__ float siluf_(float x){ return x / (1.f + __expf(-x)); }
static __device__ __forceinline__ float geluf_(float x){
  float y = 0.7978845608028654f * (x + 0.044715f * x * x * x);
  float e = __expf(2.f * y);
  return 0.5f * x * (2.f - 2.f / (e + 1.f));
}

// -------- device-scope grid barrier (all 256 blocks co-resident: 118.8KB LDS -> 1 block/CU) --------
static __device__ __forceinline__ void gsync(unsigned* bar){
  __syncthreads();
  if (threadIdx.x == 0){
    unsigned g = __hip_atomic_load(bar + 1, __ATOMIC_RELAXED, __HIP_MEMORY_SCOPE_AGENT);
    unsigned a = __hip_atomic_fetch_add(bar, 1u, __ATOMIC_ACQ_REL, __HIP_MEMORY_SCOPE_AGENT);
    if (a == (unsigned)gridDim.x - 1u){
      __hip_atomic_store(bar, 0u, __ATOMIC_RELAXED, __HIP_MEMORY_SCOPE_AGENT);
      __hip_atomic_fetch_add(bar + 1, 1u, __ATOMIC_ACQ_REL, __HIP_MEMORY_SCOPE_AGENT);
    } else {
      while (__hip_atomic_load(bar + 1, __ATOMIC_ACQUIRE, __HIP_MEMORY_SCOPE_AGENT) == g){
        __builtin_amdgcn_s_sleep(1);
      }
    }
  }
  __syncthreads();
}

// ---------------- prep: temb, offs, rope tables ----------------
__global__ void k_prep(const int* __restrict__ mask, const float* __restrict__ ts,
                       float* __restrict__ temb, int* __restrict__ offs,
                       float* __restrict__ ropec, float* __restrict__ ropes)
{
  int t = threadIdx.x;
  { // parallel mask popcount: 32 lanes per batch
    int b = t >> 5, l = t & 31;
    const int* mp = mask + b * PFXN;
    int s = 0;
    for (int k = l; k < PFXN; k += 32) s += (mp[k] != 0);
    #pragma unroll
    for (int off = 16; off >= 1; off >>= 1) s += __shfl_xor(s, off);
    if (l == 0) offs[b] = s;
  }
  for (int i = t; i < BATCH * 512; i += 256){
    int b = i >> 9, j = i & 511;
    float frac = (float)j * (1.0f / 511.0f);
    float period = 0.004f * __expf(frac * 6.907755278982137f); // ln(1000)
    float arg = (6.283185307179586f / period) * ts[b];
    float s, c; sincosf(arg, &s, &c);
    temb[b * HIDN + j] = s;
    temb[b * HIDN + 512 + j] = c;
  }
  __syncthreads();
  for (int i = t; i < BATCH * AHOR * 128; i += 256){
    int d = i & 127, bt = i >> 7, b = bt / AHOR, tt = bt % AHOR;
    float inv = __expf(-((float)d * (1.f / 128.f)) * 9.210340371976184f); // ln(10000)
    float arg = (float)(offs[b] + tt) * inv;
    float s, c; sincosf(arg, &s, &c);
    ropec[i] = c; ropes[i] = s;
  }
}

// ---------------- tiny M=8 GEMM (1024x1024) + silu ----------------
__global__ void k_tproj(const float* __restrict__ X, const float* __restrict__ W,
                        const float* __restrict__ bias, float* __restrict__ out)
{
  __shared__ float xs[BATCH * HIDN];
  __shared__ float red[BATCH][8][32];
  int t = threadIdx.x;
  for (int i = t; i < BATCH * HIDN; i += 256) xs[i] = X[i];
  __syncthreads();
  int c = t & 31, kp = t >> 5;
  int c0 = blockIdx.x * 32;
  float acc[BATCH];
  #pragma unroll
  for (int b = 0; b < BATCH; ++b) acc[b] = 0.f;
  for (int k = kp * 128; k < kp * 128 + 128; ++k){
    float w = W[(size_t)k * HIDN + c0 + c];
    #pragma unroll
    for (int b = 0; b < BATCH; ++b) acc[b] += xs[b * HIDN + k] * w;
  }
  #pragma unroll
  for (int b = 0; b < BATCH; ++b) red[b][kp][c] = acc[b];
  __syncthreads();
  int b2 = t >> 5, c2 = t & 31;
  float s = bias[c0 + c2];
  #pragma unroll
  for (int kp2 = 0; kp2 < 8; ++kp2) s += red[b2][kp2][c2];
  out[b2 * HIDN + c0 + c2] = siluf_(s);
}

// ---------------- ada partial: K-split x4, batched f4 loads ----------------
__global__ void k_ada_part(const float* __restrict__ cond, const float* __restrict__ A1,
                           const float* __restrict__ A2, const float* __restrict__ Af,
                           float* __restrict__ adap)
{
  __shared__ float cs[BATCH * 256];
  int t = threadIdx.x; // 256
  int y = blockIdx.y, ks = blockIdx.z;
  int k0 = ks * 256;
  for (int i = t; i < BATCH * 256; i += 256){
    int b = i >> 8, kk = i & 255;
    cs[i] = cond[b * HIDN + k0 + kk];
  }
  __syncthreads();
  const float* A = (y < NLAY) ? (A1 + (size_t)y * HIDN * 3072)
                  : (y < 2 * NLAY) ? (A2 + (size_t)(y - NLAY) * HIDN * 3072) : Af;
  int n = (blockIdx.x * 256 + t) * 4; // 0..3068
  f4 acc[BATCH];
  #pragma unroll
  for (int b = 0; b < BATCH; ++b) acc[b] = (f4){0.f,0.f,0.f,0.f};
  const float* ap = A + (size_t)k0 * 3072 + n;
  for (int kk = 0; kk < 256; kk += 8){
    f4 av[8];
    #pragma unroll
    for (int j = 0; j < 8; ++j) av[j] = *(const f4*)(ap + (size_t)(kk + j) * 3072);
    #pragma unroll
    for (int j = 0; j < 8; ++j){
      #pragma unroll
      for (int b = 0; b < BATCH; ++b) acc[b] += av[j] * cs[b * 256 + kk + j];
    }
  }
  int comp = n >> 10, nn = n & 1023;
  float* o = adap + (size_t)ks * ADASL + ((size_t)y * 3 + comp) * BATCH * HIDN + nn;
  #pragma unroll
  for (int b = 0; b < BATCH; ++b) *(f4*)(o + b * HIDN) = acc[b];
}

__global__ void k_ada_red(const float* __restrict__ adap, float* __restrict__ ada)
{
  size_t i = ((size_t)blockIdx.x * 256 + threadIdx.x) * 8;
  f4 a0 = {0,0,0,0}, a1 = {0,0,0,0};
  #pragma unroll
  for (int ks = 0; ks < 4; ++ks){
    const float* p = adap + (size_t)ks * ADASL + i;
    a0 += *(const f4*)p;
    a1 += *(const f4*)(p + 4);
  }
  *(f4*)(ada + i) = a0;
  *(f4*)(ada + i + 4) = a1;
}

// ---------------- h0 = x_t @ W_act_in + b ----------------
__global__ void k_hin(const float* __restrict__ xt, const float* __restrict__ W,
                      const float* __restrict__ bias, float* __restrict__ h)
{
  int r = blockIdx.x; // 0..399
  int t = threadIdx.x; int c0 = t * 4;
  __shared__ float xs[ADIMN];
  if (t < ADIMN) xs[t] = xt[r * ADIMN + t];
  __syncthreads();
  float a0 = bias[c0], a1 = bias[c0+1], a2 = bias[c0+2], a3 = bias[c0+3];
  for (int k = 0; k < ADIMN; ++k){
    float x = xs[k];
    const float* wp = W + k * HIDN + c0;
    a0 += x * wp[0]; a1 += x * wp[1]; a2 += x * wp[2]; a3 += x * wp[3];
  }
  float* hp = h + (size_t)r * HIDN + c0;
  hp[0] = a0; hp[1] = a1; hp[2] = a2; hp[3] = a3;
}

// ---------------- standalone RMS+AdaNorm (mode 0, prologue only) ----------------
__global__ void k_resnorm0(const float* __restrict__ base, const float* __restrict__ sc,
                           const float* __restrict__ sh, u16* __restrict__ fragA)
{
  __shared__ float redl[4];
  int t = threadIdx.x;
  int c = t * 4;
  for (int i = 0; i < 4; ++i){
    int r = blockIdx.x * 4 + i;
    bool live = (r < MR);
    float4 v = {0.f,0.f,0.f,0.f};
    int b = live ? (r / AHOR) : 0;
    if (live) v = *(const float4*)(base + (size_t)r * HIDN + c);
    float ss = v.x*v.x + v.y*v.y + v.z*v.z + v.w*v.w;
    #pragma unroll
    for (int off = 1; off < 64; off <<= 1) ss += __shfl_xor(ss, off);
    if ((t & 63) == 0) redl[t >> 6] = ss;
    __syncthreads();
    float tot = redl[0] + redl[1] + redl[2] + redl[3];
    __syncthreads();
    u16* dst = fragA + ((size_t)(c >> 3)) * MP * 8 + (size_t)r * 8 + (c & 7);
    ushort4 ov;
    if (live){
      float rstd = rsqrtf(tot * (1.0f / HIDN) + EPSV);
      const float4 scp = *(const float4*)(sc + b * HIDN + c);
      const float4 shp = *(const float4*)(sh + b * HIDN + c);
      ov.x = f2bf(v.x * rstd * (1.f + scp.x) + shp.x);
      ov.y = f2bf(v.y * rstd * (1.f + scp.y) + shp.y);
      ov.z = f2bf(v.z * rstd * (1.f + scp.z) + shp.z);
      ov.w = f2bf(v.w * rstd * (1.f + scp.w) + shp.w);
    } else {
      ov.x = ov.y = ov.z = ov.w = 0;
    }
    *(ushort4*)dst = ov;
  }
}

// ---------------- GEMM core 64-col: double-buffered LDS, depth-2 W prefetch ----------------
template<int NOUTER>
static __device__ __forceinline__ void gemm_core64(
    const u16* __restrict__ fa,
    const float* __restrict__ Wa, int cb0,
    const float* __restrict__ Wb, int cb1,
    int wN, int kc0, u16* lds, f4 acc[4][4])
{
  const int tid = threadIdx.x;
  const int lane = tid & 63, wave = tid >> 6;
  const int l15 = lane & 15, g = lane >> 4;
  const int wrow = wave * 64;
  const int sn = tid & 63, skb = (tid >> 6) * 8;
  const float* wbase = (sn < 32) ? (Wa + cb0 + sn) : (Wb + cb1 + (sn - 32));
  const size_t krow0 = (size_t)kc0 * 8 + skb;
  float pre[2][8];
  #pragma unroll
  for (int j = 0; j < 8; ++j) pre[0][j] = wbase[(krow0 + j) * wN];
  if (NOUTER > 1){
    #pragma unroll
    for (int j = 0; j < 8; ++j) pre[1][j] = wbase[(krow0 + 64 + j) * wN];
  }
  { u32* dst = (u32*)(lds + sn * 88 + skb);
    dst[0] = pack2(pre[0][0], pre[0][1]); dst[1] = pack2(pre[0][2], pre[0][3]);
    dst[2] = pack2(pre[0][4], pre[0][5]); dst[3] = pack2(pre[0][6], pre[0][7]); }
  __syncthreads();
  #pragma unroll
  for (int ko = 0; ko < NOUTER; ++ko){
    u16* ldsr = lds + (ko & 1) * (64 * 88);
    bh8 a[2][4];
    #pragma unroll
    for (int kk = 0; kk < 2; ++kk){
      int kcg = kc0 + ko * 8 + kk * 4 + g;
      const u16* ap = fa + ((size_t)kcg * MP + wrow + l15) * 8;
      #pragma unroll
      for (int mf = 0; mf < 4; ++mf) a[kk][mf] = *(const bh8*)(ap + mf * 128);
    }
    if (ko + 2 < NOUTER){
      #pragma unroll
      for (int j = 0; j < 8; ++j) pre[ko & 1][j] = wbase[(krow0 + (size_t)(ko + 2) * 64 + j) * wN];
    }
    #pragma unroll
    for (int kk = 0; kk < 2; ++kk){
      bh8 bb[4];
      #pragma unroll
      for (int nf = 0; nf < 4; ++nf) bb[nf] = *(const bh8*)(ldsr + (nf * 16 + l15) * 88 + kk * 32 + g * 8);
      #pragma unroll
      for (int mf = 0; mf < 4; ++mf)
        #pragma unroll
        for (int nf = 0; nf < 4; ++nf)
          acc[mf][nf] = MFMA(a[kk][mf], bb[nf], acc[mf][nf]);
    }
    if (ko + 1 < NOUTER){
      u16* ldsw = lds + ((ko + 1) & 1) * (64 * 88);
      u32* dst = (u32*)(ldsw + sn * 88 + skb);
      const float* p = pre[(ko + 1) & 1];
      dst[0] = pack2(p[0], p[1]); dst[1] = pack2(p[2], p[3]);
      dst[2] = pack2(p[4], p[5]); dst[3] = pack2(p[6], p[7]);
      __syncthreads();
    }
  }
}

// ---------------- GEMM core 32-col wide-K: 128 k/iter, double-buffered ----------------
template<int NOUTER>
static __device__ __forceinline__ void gemm_core32w(
    const u16* __restrict__ fa,
    const float* __restrict__ Wa, int cb0,
    const float* __restrict__ Wb, int cb1,
    int wN, u16* lds, f4 acc[4][2])
{
  const int tid = threadIdx.x;
  const int lane = tid & 63, wave = tid >> 6;
  const int l15 = lane & 15, g = lane >> 4;
  const int wrow = wave * 64;
  const int sc = tid & 31, kq = tid >> 5;
  const int kb = kq * 8;
  const float* wbase = (sc < 16) ? (Wa + cb0 + sc) : (Wb + cb1 + (sc - 16));
  float pre[2][8];
  #pragma unroll
  for (int j = 0; j < 8; ++j) pre[0][j] = wbase[(size_t)(kb + j) * wN];
  if (NOUTER > 1){
    #pragma unroll
    for (int j = 0; j < 8; ++j) pre[1][j] = wbase[(size_t)(128 + kb + j) * wN];
  }
  { u32* dst = (u32*)(lds + sc * 136 + kb);
    dst[0] = pack2(pre[0][0], pre[0][1]); dst[1] = pack2(pre[0][2], pre[0][3]);
    dst[2] = pack2(pre[0][4], pre[0][5]); dst[3] = pack2(pre[0][6], pre[0][7]); }
  __syncthreads();
  #pragma unroll
  for (int ko = 0; ko < NOUTER; ++ko){
    u16* ldsr = lds + (ko & 1) * (32 * 136);
    bh8 a[2][4];
    #pragma unroll
    for (int kk = 0; kk < 2; ++kk){
      int kcg = ko * 16 + kk * 4 + g;
      const u16* ap = fa + ((size_t)kcg * MP + wrow + l15) * 8;
      #pragma unroll
      for (int mf = 0; mf < 4; ++mf) a[kk][mf] = *(const bh8*)(ap + mf * 128);
    }
    if (ko + 2 < NOUTER){
      #pragma unroll
      for (int j = 0; j < 8; ++j) pre[ko & 1][j] = wbase[(size_t)((ko + 2) * 128 + kb + j) * wN];
    }
    #pragma unroll
    for (int kk = 0; kk < 2; ++kk){
      bh8 bb[2];
      #pragma unroll
      for (int nf = 0; nf < 2; ++nf) bb[nf] = *(const bh8*)(ldsr + (nf * 16 + l15) * 136 + kk * 32 + g * 8);
      #pragma unroll
      for (int mf = 0; mf < 4; ++mf){
        acc[mf][0] = MFMA(a[kk][mf], bb[0], acc[mf][0]);
        acc[mf][1] = MFMA(a[kk][mf], bb[1], acc[mf][1]);
      }
    }
    #pragma unroll
    for (int kk = 2; kk < 4; ++kk){
      int kcg = ko * 16 + kk * 4 + g;
      const u16* ap = fa + ((size_t)kcg * MP + wrow + l15) * 8;
      #pragma unroll
      for (int mf = 0; mf < 4; ++mf) a[kk - 2][mf] = *(const bh8*)(ap + mf * 128);
    }
    #pragma unroll
    for (int kk = 2; kk < 4; ++kk){
      bh8 bb[2];
      #pragma unroll
      for (int nf = 0; nf < 2; ++nf) bb[nf] = *(const bh8*)(ldsr + (nf * 16 + l15) * 136 + kk * 32 + g * 8);
      #pragma unroll
      for (int mf = 0; mf < 4; ++mf){
        acc[mf][0] = MFMA(a[kk - 2][mf], bb[0], acc[mf][0]);
        acc[mf][1] = MFMA(a[kk - 2][mf], bb[1], acc[mf][1]);
      }
    }
    if (ko + 1 < NOUTER){
      u16* ldsw = lds + ((ko + 1) & 1) * (32 * 136);
      u32* dst = (u32*)(ldsw + sc * 136 + kb);
      const float* p = pre[(ko + 1) & 1];
      dst[0] = pack2(p[0], p[1]); dst[1] = pack2(p[2], p[3]);
      dst[2] = pack2(p[4], p[5]); dst[3] = pack2(p[6], p[7]);
      __syncthreads();
    }
  }
}

// ================= mega-kernel phase bodies (512 threads each) =================

static __device__ __forceinline__ void ph_qkv(int task,
    const u16* n1, const float* Wq, const float* Wk, const float* Wv,
    u16* qkvp, u16* lds)
{
  int bx = task % 40, ksl = task / 40;
  const float* W; int wN, cb0, colbase;
  if (bx < 32){ W = Wq; wN = NHEAD * HD; cb0 = bx * 64; colbase = bx * 64; }
  else if (bx < 36){ W = Wk; wN = HD; cb0 = (bx - 32) * 64; colbase = 2048 + cb0; }
  else { W = Wv; wN = HD; cb0 = (bx - 36) * 64; colbase = 2304 + cb0; }
  f4 acc[4][4];
  #pragma unroll
  for (int i = 0; i < 4; ++i)
    #pragma unroll
    for (int j = 0; j < 4; ++j) acc[i][j] = (f4){0.f, 0.f, 0.f, 0.f};
  gemm_core64<4>(n1, W, cb0, W, cb0 + 32, wN, ksl * 32, lds, acc);
  int tid = threadIdx.x, lane = tid & 63, wave = tid >> 6, l15 = lane & 15, g = lane >> 4;
  int wrow = wave * 64;
  #pragma unroll
  for (int mf = 0; mf < 4; ++mf)
    #pragma unroll
    for (int r = 0; r < 4; ++r){
      int row = wrow + mf * 16 + 4 * g + r;
      #pragma unroll
      for (int nf = 0; nf < 4; ++nf)
        qkvp[((size_t)ksl * MP + row) * 2560 + colbase + nf * 16 + l15] = f2bf(acc[mf][nf][r]);
    }
}

static __device__ __forceinline__ void ph_rope(int task,
    const u16* qkvp, const float* ropec, const float* ropes,
    u16* qf, u16* ks, u16* vs)
{
  int tid = threadIdx.x;
  int rl = tid & 255, rr = tid >> 8;
  int r = task * 2 + rr; // 0..399
  int b = r / AHOR, tt = r - b * AHOR;
  const u16* base = qkvp + (size_t)r * 2560;
  const size_t SL = (size_t)MP * 2560;
  #pragma unroll
  for (int i = 0; i < 4; ++i){
    int idx = rl + 256 * i; int head = idx >> 7, dA = idx & 127;
    int cL = head * 256 + dA, cH = cL + 128;
    float lo = bf2f(base[cL]) + bf2f(base[SL + cL]) + bf2f(base[2 * SL + cL]) + bf2f(base[3 * SL + cL]);
    float hi = bf2f(base[cH]) + bf2f(base[SL + cH]) + bf2f(base[2 * SL + cH]) + bf2f(base[3 * SL + cH]);
    float cz = ropec[(size_t)r * 128 + dA], sz = ropes[(size_t)r * 128 + dA];
    float oA = (lo * cz - hi * sz) * QSCALE;
    float oB = (hi * cz + lo * sz) * QSCALE;
    int rowp = head * AHOR + tt;
    int dB = dA + 128;
    qf[((size_t)(b * 32 + (dA >> 3))) * MP * 8 + (size_t)rowp * 8 + (dA & 7)] = f2bf(oA);
    qf[((size_t)(b * 32 + (dB >> 3))) * MP * 8 + (size_t)rowp * 8 + (dB & 7)] = f2bf(oB);
  }
  if (rl < 128){
    int dA = rl, cL = 2048 + dA, cH = cL + 128;
    float lo = bf2f(base[cL]) + bf2f(base[SL + cL]) + bf2f(base[2 * SL + cL]) + bf2f(base[3 * SL + cL]);
    float hi = bf2f(base[cH]) + bf2f(base[SL + cH]) + bf2f(base[2 * SL + cH]) + bf2f(base[3 * SL + cH]);
    float cz = ropec[(size_t)r * 128 + dA], sz = ropes[(size_t)r * 128 + dA];
    ks[(size_t)r * HD + dA] = f2bf(lo * cz - hi * sz);
    ks[(size_t)r * HD + dA + 128] = f2bf(hi * cz + lo * sz);
  }
  {
    int c = 2304 + rl;
    float v = bf2f(base[c]) + bf2f(base[SL + c]) + bf2f(base[2 * SL + c]) + bf2f(base[3 * SL + c]);
    vs[(size_t)r * HD + rl] = f2bf(v);
  }
}

static __device__ __forceinline__ void ph_attn(int task, int layer,
    const u16* qf, const u16* kss, const u16* vss,
    const float* pk, const float* pv, const int* mask,
    u16* opart, float* mrow, float* lrow, u16* kv, u16* plds)
{
  __syncthreads(); // protect smem reuse across phases
  int s = task % NSTR, b = task / NSTR;
  int tid = threadIdx.x, lane = tid & 63, wave = tid >> 6, l15 = lane & 15, g = lane >> 4;
  int wrow = wave * 64;
  int key = tid >> 3, dblk = (tid & 7) * 32;
  int kg = s * 64 + key;
  { // stage K tile (bf16) direct to LDS
    u32* dst = (u32*)(kv + key * 264 + dblk);
    if (kg < PFXN){
      const float4* src = (const float4*)(pk + (((size_t)b * NLAY + layer) * PFXN + kg) * HD + dblk);
      #pragma unroll
      for (int j = 0; j < 8; ++j){ float4 v = src[j]; dst[2*j] = pack2(v.x, v.y); dst[2*j+1] = pack2(v.z, v.w); }
    } else if (kg < SEQN){
      const u32* src = (const u32*)(kss + ((size_t)b * AHOR + (kg - PFXN)) * HD + dblk);
      #pragma unroll
      for (int j = 0; j < 16; ++j) dst[j] = src[j];
    } else {
      #pragma unroll
      for (int j = 0; j < 16; ++j) dst[j] = 0;
    }
  }
  // prefetch V tile into registers
  float vreg[32];
  if (kg < PFXN){
    const float4* src = (const float4*)(pv + (((size_t)b * NLAY + layer) * PFXN + kg) * HD + dblk);
    #pragma unroll
    for (int j = 0; j < 8; ++j){ float4 v = src[j]; vreg[4*j] = v.x; vreg[4*j+1] = v.y; vreg[4*j+2] = v.z; vreg[4*j+3] = v.w; }
  } else if (kg < SEQN){
    const u32* src = (const u32*)(vss + ((size_t)b * AHOR + (kg - PFXN)) * HD + dblk);
    #pragma unroll
    for (int j = 0; j < 16; ++j){ u32 u = src[j]; vreg[2*j] = bf2f((u16)(u & 0xFFFF)); vreg[2*j+1] = bf2f((u16)(u >> 16)); }
  } else {
    #pragma unroll
    for (int j = 0; j < 32; ++j) vreg[j] = 0.f;
  }
  bool valid[4];
  #pragma unroll
  for (int nf = 0; nf < 4; ++nf){
    int kgc = s * 64 + nf * 16 + l15;
    valid[nf] = (kgc < PFXN) ? (mask[b * PFXN + kgc] != 0) : (kgc < SEQN);
  }
  __syncthreads();
  // S = (Q*scale) K^T
  f4 acc[4][4];
  #pragma unroll
  for (int i = 0; i < 4; ++i)
    #pragma unroll
    for (int j = 0; j < 4; ++j) acc[i][j] = (f4){0.f,0.f,0.f,0.f};
  const u16* qb = qf + (size_t)b * 32 * MP * 8;
  #pragma unroll
  for (int ko = 0; ko < 4; ++ko)
    #pragma unroll
    for (int kk = 0; kk < 2; ++kk){
      int kc = ko * 8 + kk * 4 + g;
      bh8 a[4], bb[4];
      const u16* ap = qb + ((size_t)kc * MP + wrow + l15) * 8;
      #pragma unroll
      for (int mf = 0; mf < 4; ++mf) a[mf] = *(const bh8*)(ap + mf * 128);
      #pragma unroll
      for (int nf = 0; nf < 4; ++nf) bb[nf] = *(const bh8*)(kv + (nf * 16 + l15) * 264 + ko * 64 + kk * 32 + g * 8);
      #pragma unroll
      for (int mf = 0; mf < 4; ++mf)
        #pragma unroll
        for (int nf = 0; nf < 4; ++nf) acc[mf][nf] = MFMA(a[mf], bb[nf], acc[mf][nf]);
    }
  #pragma unroll
  for (int nf = 0; nf < 4; ++nf) if (!valid[nf]){
    #pragma unroll
    for (int mf = 0; mf < 4; ++mf){
      acc[mf][nf][0] = NEGV; acc[mf][nf][1] = NEGV; acc[mf][nf][2] = NEGV; acc[mf][nf][3] = NEGV;
    }
  }
  // per-strip softmax
  #pragma unroll
  for (int mf = 0; mf < 4; ++mf)
    #pragma unroll
    for (int r = 0; r < 4; ++r){
      float m0 = fmaxf(fmaxf(acc[mf][0][r], acc[mf][1][r]), fmaxf(acc[mf][2][r], acc[mf][3][r]));
      #pragma unroll
      for (int off = 1; off < 16; off <<= 1) m0 = fmaxf(m0, __shfl_xor(m0, off));
      int row = wrow + mf * 16 + 4 * g + r;
      float sum = 0.f;
      #pragma unroll
      for (int nf = 0; nf < 4; ++nf){
        float p = __expf(acc[mf][nf][r] - m0);
        sum += p;
        plds[row * 72 + nf * 16 + l15] = f2bf(p);
      }
      #pragma unroll
      for (int off = 1; off < 16; off <<= 1) sum += __shfl_xor(sum, off);
      if (l15 == 0){
        mrow[((size_t)b * NSTR + s) * MP + row] = m0;
        lrow[((size_t)b * NSTR + s) * MP + row] = sum;
      }
    }
  __syncthreads();
  { // write V^T from regs with skewed layout
    #pragma unroll
    for (int j = 0; j < 32; ++j){
      int d = dblk + j;
      kv[d * 88 + ((d >> 5) & 3) * 8 + key] = f2bf(vreg[j]);
    }
  }
  __syncthreads();
  // O_part = P V
  #pragma unroll
  for (int dc = 0; dc < 4; ++dc){
    f4 oc[4][4];
    #pragma unroll
    for (int i = 0; i < 4; ++i)
      #pragma unroll
      for (int j = 0; j < 4; ++j) oc[i][j] = (f4){0.f,0.f,0.f,0.f};
    #pragma unroll
    for (int kk = 0; kk < 2; ++kk){
      bh8 a[4], bb[4];
      #pragma unroll
      for (int mf = 0; mf < 4; ++mf) a[mf] = *(const bh8*)(plds + (wrow + mf * 16 + l15) * 72 + kk * 32 + g * 8);
      #pragma unroll
      for (int nf = 0; nf < 4; ++nf){
        int dcol = dc * 64 + nf * 16 + l15;
        bb[nf] = *(const bh8*)(kv + dcol * 88 + ((dcol >> 5) & 3) * 8 + kk * 32 + g * 8);
      }
      #pragma unroll
      for (int mf = 0; mf < 4; ++mf)
        #pragma unroll
        for (int nf = 0; nf < 4; ++nf) oc[mf][nf] = MFMA(a[mf], bb[nf], oc[mf][nf]);
    }
    #pragma unroll
    for (int mf = 0; mf < 4; ++mf)
      #pragma unroll
      for (int r = 0; r < 4; ++r){
        int row = wrow + mf * 16 + 4 * g + r;
        if (row < MR){
          #pragma unroll
          for (int nf = 0; nf < 4; ++nf){
            int d = dc * 64 + nf * 16 + l15;
            opart[(((size_t)b * NSTR + s) * MR + row) * HD + d] = f2bf(oc[mf][nf][r]);
          }
        }
      }
  }
}

static __device__ __forceinline__ void ph_comb(int task,
    const u16* opart, const float* mrow, const float* lrow, u16* ao)
{
  int rg = task % 25, b = task / 25;
  int tid = threadIdx.x;
  int d = tid & 255, half = tid >> 8;
  int r0 = rg * 16 + half * 8;
  for (int i = 0; i < 8; ++i){
    int row = r0 + i;
    float M = -3.0e38f;
    for (int s2 = 0; s2 < NSTR; ++s2) M = fmaxf(M, mrow[((size_t)b * NSTR + s2) * MP + row]);
    float L = 0.f, o = 0.f;
    for (int s2 = 0; s2 < NSTR; ++s2){
      float w = __expf(mrow[((size_t)b * NSTR + s2) * MP + row] - M);
      L += w * lrow[((size_t)b * NSTR + s2) * MP + row];
      o += w * bf2f(opart[(((size_t)b * NSTR + s2) * MR + row) * HD + d]);
    }
    float val = o / L;
    int h = row / AHOR, tt = row - h * AHOR;
    int col = h * HD + d;
    int rgl = b * AHOR + tt;
    ao[((size_t)(col >> 3)) * MP * 8 + (size_t)rgl * 8 + (col & 7)] = f2bf(val);
  }
}

template<int NOUTER>
static __device__ __forceinline__ void ph_gemm(int task,
    const u16* fa, const float* W, int wN, int kcPerSlice, u16* outp, u16* lds)
{
  int nx = task & 15, ksl = task >> 4;
  int n0 = nx * 64;
  f4 acc[4][4];
  #pragma unroll
  for (int i = 0; i < 4; ++i)
    #pragma unroll
    for (int j = 0; j < 4; ++j) acc[i][j] = (f4){0.f,0.f,0.f,0.f};
  gemm_core64<NOUTER>(fa, W, n0, W, n0 + 32, wN, ksl * kcPerSlice, lds, acc);
  int tid = threadIdx.x, lane = tid & 63, wave = tid >> 6, l15 = lane & 15, g = lane >> 4;
  int wrow = wave * 64;
  #pragma unroll
  for (int mf = 0; mf < 4; ++mf)
    #pragma unroll
    for (int r = 0; r < 4; ++r){
      int row = wrow + mf * 16 + 4 * g + r;
      #pragma unroll
      for (int nf = 0; nf < 4; ++nf)
        outp[((size_t)ksl * MP + row) * 1024 + n0 + nf * 16 + l15] = f2bf(acc[mf][nf][r]);
    }
}

static __device__ __forceinline__ void ph_mlpup(int task,
    const u16* n2, const float* Wg, const float* Wu, u16* mlpf, u16* lds)
{
  int n0 = task * 16;
  f4 acc[4][2];
  #pragma unroll
  for (int i = 0; i < 4; ++i)
    #pragma unroll
    for (int j = 0; j < 2; ++j) acc[i][j] = (f4){0.f,0.f,0.f,0.f};
  gemm_core32w<8>(n2, Wg, n0, Wu, n0, DMLP, lds, acc);
  int tid = threadIdx.x, lane = tid & 63, wave = tid >> 6, l15 = lane & 15, g = lane >> 4;
  int wrow = wave * 64;
  #pragma unroll
  for (int mf = 0; mf < 4; ++mf)
    #pragma unroll
    for (int r = 0; r < 4; ++r){
      int row = wrow + mf * 16 + 4 * g + r;
      int col = n0 + l15;
      float gg = acc[mf][0][r], uu = acc[mf][1][r];
      float act = geluf_(gg) * uu;
      mlpf[((size_t)(col >> 3)) * MP * 8 + (size_t)row * 8 + (col & 7)] = f2bf(act);
    }
}

static __device__ __forceinline__ void ph_resnorm(int task, int np,
    const float* base, const u16* parts, const float* gate, const float* sc,
    const float* sh, float* outres, u16* fragA, float* redl)
{
  int tid = threadIdx.x;
  int tl = tid & 255, sub = tid >> 8;
  int c = tl * 4;
  int wv = tid >> 6;
  for (int i = 0; i < 2; ++i){
    int r = task * 4 + sub * 2 + i;
    bool live = (r < MR);
    float4 v = {0.f,0.f,0.f,0.f};
    int b = live ? (r / AHOR) : 0;
    if (live){
      v = *(const float4*)(base + (size_t)r * HIDN + c);
      float s0 = 0, s1 = 0, s2 = 0, s3 = 0;
      #pragma unroll 4
      for (int p = 0; p < np; ++p){
        ushort4 u4 = *(const ushort4*)(parts + ((size_t)p * MP + r) * HIDN + c);
        s0 += bf2f(u4.x); s1 += bf2f(u4.y); s2 += bf2f(u4.z); s3 += bf2f(u4.w);
      }
      float4 gp = *(const float4*)(gate + b * HIDN + c);
      v.x += gp.x * s0; v.y += gp.y * s1; v.z += gp.z * s2; v.w += gp.w * s3;
      *(float4*)(outres + (size_t)r * HIDN + c) = v;
    }
    float ss = v.x*v.x + v.y*v.y + v.z*v.z + v.w*v.w;
    #pragma unroll
    for (int off = 1; off < 64; off <<= 1) ss += __shfl_xor(ss, off);
    if ((tid & 63) == 0) redl[wv] = ss;
    __syncthreads();
    float tot = redl[sub * 4] + redl[sub * 4 + 1] + redl[sub * 4 + 2] + redl[sub * 4 + 3];
    __syncthreads();
    u16* dst = fragA + ((size_t)(c >> 3)) * MP * 8 + (size_t)r * 8 + (c & 7);
    ushort4 ov;
    if (live){
      float rstd = rsqrtf(tot * (1.0f / HIDN) + EPSV);
      const float4 scp = *(const float4*)(sc + b * HIDN + c);
      const float4 shp = *(const float4*)(sh + b * HIDN + c);
      ov.x = f2bf(v.x * rstd * (1.f + scp.x) + shp.x);
      ov.y = f2bf(v.y * rstd * (1.f + scp.y) + shp.y);
      ov.z = f2bf(v.z * rstd * (1.f + scp.z) + shp.z);
      ov.w = f2bf(v.w * rstd * (1.f + scp.w) + shp.w);
    } else {
      ov.x = ov.y = ov.z = ov.w = 0;
    }
    *(ushort4*)dst = ov;
  }
}

// ================= the persistent 18-layer mega-kernel =================
__global__ __launch_bounds__(512, 2) void k_layers(
    const float* __restrict__ pk, const float* __restrict__ pv, const int* __restrict__ msk,
    const float* __restrict__ ropec, const float* __restrict__ ropes,
    const float* __restrict__ Wq, const float* __restrict__ Wk, const float* __restrict__ Wv,
    const float* __restrict__ Wo, const float* __restrict__ Wg, const float* __restrict__ Wu,
    const float* __restrict__ Wd, const float* __restrict__ ada,
    float* h, float* h1, u16* n1, u16* n2,
    u16* qkvp, u16* qf, u16* kss, u16* vss,
    u16* opart, float* mrow, float* lrow, u16* ao,
    u16* opp, u16* mlpf, u16* mdp, unsigned* bar)
{
  __shared__ u16 smem[256 * 88 + 512 * 72]; // attn: kv + plds; gemms use prefix
  __shared__ float redl[8];
  u16* kv = smem;
  u16* plds = smem + 256 * 88;
  const int bid = blockIdx.x, G = gridDim.x;

  for (int l = 0; l < NLAY; ++l){
    const float* Wq_l = Wq + (size_t)l * HIDN * NHEAD * HD;
    const float* Wk_l = Wk + (size_t)l * HIDN * HD;
    const float* Wv_l = Wv + (size_t)l * HIDN * HD;
    const float* Wo_l = Wo + (size_t)l * 2048 * 1024;
    const float* Wg_l = Wg + (size_t)l * HIDN * DMLP;
    const float* Wu_l = Wu + (size_t)l * HIDN * DMLP;
    const float* Wd_l = Wd + (size_t)l * DMLP * 1024;
    const float* g1  = ada + ((size_t)l * 3 + 2) * BATCH * HIDN;
    const float* sc2 = ada + ((size_t)(NLAY + l) * 3 + 0) * BATCH * HIDN;
    const float* sh2 = ada + ((size_t)(NLAY + l) * 3 + 1) * BATCH * HIDN;
    const float* g2  = ada + ((size_t)(NLAY + l) * 3 + 2) * BATCH * HIDN;
    int ny = (l < NLAY - 1) ? (l + 1) : 36;
    const float* nsc = ada + ((size_t)ny * 3 + 0) * BATCH * HIDN;
    const float* nsh = ada + ((size_t)ny * 3 + 1) * BATCH * HIDN;

    for (int t = bid; t < 160; t += G) ph_qkv(t, n1, Wq_l, Wk_l, Wv_l, qkvp, smem);
    gsync(bar);
    for (int t = bid; t < 200; t += G) ph_rope(t, qkvp, ropec, ropes, qf, kss, vss);
    gsync(bar);
    for (int t = bid; t < NSTR * BATCH; t += G) ph_attn(t, l, qf, kss, vss, pk, pv, msk, opart, mrow, lrow, kv, plds);
    gsync(bar);
    for (int t = bid; t < 200; t += G) ph_comb(t, opart, mrow, lrow, ao);
    gsync(bar);
    for (int t = bid; t < 128; t += G) ph_gemm<4>(t, ao, Wo_l, 1024, 32, opp, smem);
    gsync(bar);
    for (int t = bid; t < 128; t += G) ph_resnorm(t, 8, h, opp, g1, sc2, sh2, h1, n2, redl);
    gsync(bar);
    for (int t = bid; t < 256; t += G) ph_mlpup(t, n2, Wg_l, Wu_l, mlpf, smem);
    gsync(bar);
    for (int t = bid; t < 128; t += G) ph_gemm<8>(t, mlpf, Wd_l, 1024, 64, mdp, smem);
    gsync(bar);
    for (int t = bid; t < 128; t += G) ph_resnorm(t, 8, h1, mdp, g2, nsc, nsh, h, n1, redl);
    gsync(bar);
  }
}

// ---------------- final: out = nf @ W_act_out + b ----------------
__global__ void k_out(const u16* __restrict__ nfr, const float* __restrict__ W,
                      const float* __restrict__ bias, float* __restrict__ out)
{
  int t = threadIdx.x;
  int row = blockIdx.x * 8 + (t >> 5);
  int c = t & 31;
  float acc = bias[c];
  for (int k = 0; k < HIDN; ++k)
    acc += bf2f(nfr[((size_t)(k >> 3)) * MP * 8 + (size_t)row * 8 + (k & 7)]) * W[k * ADIMN + c];
  out[row * ADIMN + c] = acc;
}

extern "C" void kernel_launch(void* const* d_in, const int* in_sizes, int n_in,
                              void* d_out, int out_size, void* d_ws, size_t ws_size,
                              hipStream_t stream)
{
  const float* pk  = (const float*)d_in[0];
  const float* pv  = (const float*)d_in[1];
  const int*   msk = (const int*)d_in[2];
  const float* xt  = (const float*)d_in[3];
  const float* ts  = (const float*)d_in[4];
  const float* Wq  = (const float*)d_in[5];
  const float* Wk  = (const float*)d_in[6];
  const float* Wv  = (const float*)d_in[7];
  const float* Wo  = (const float*)d_in[8];
  const float* Wg  = (const float*)d_in[9];
  const float* Wu  = (const float*)d_in[10];
  const float* Wd  = (const float*)d_in[11];
  const float* A1  = (const float*)d_in[12];
  const float* A2  = (const float*)d_in[13];
  const float* Af  = (const float*)d_in[14];
  const float* Wai = (const float*)d_in[15];
  const float* bai = (const float*)d_in[16];
  const float* Wao = (const float*)d_in[17];
  const float* bao = (const float*)d_in[18];
  const float* Wti = (const float*)d_in[19];
  const float* bti = (const float*)d_in[20];
  const float* Wto = (const float*)d_in[21];
  const float* bto = (const float*)d_in[22];

  char* w = (char*)d_ws;
  size_t off = 0;
  auto alloc = [&](size_t bytes) -> char* {
    char* p = w + off; off += (bytes + 255) & ~(size_t)255; return p;
  };
  float* temb  = (float*)alloc((size_t)BATCH * HIDN * 4);
  float* ttmp  = (float*)alloc((size_t)BATCH * HIDN * 4);
  float* cond  = (float*)alloc((size_t)BATCH * HIDN * 4);
  int*   offs  = (int*)alloc(BATCH * 4);
  float* ropec = (float*)alloc((size_t)BATCH * AHOR * 128 * 4);
  float* ropes = (float*)alloc((size_t)BATCH * AHOR * 128 * 4);
  float* ada   = (float*)alloc(ADASL * 4);
  float* adap  = (float*)alloc(4 * ADASL * 4);
  float* h     = (float*)alloc((size_t)MR * HIDN * 4);
  float* h1    = (float*)alloc((size_t)MR * HIDN * 4);
  u16*   n1    = (u16*)alloc((size_t)128 * MP * 8 * 2);
  u16*   n2    = (u16*)alloc((size_t)128 * MP * 8 * 2);
  u16*   qkvp  = (u16*)alloc((size_t)4 * MP * 2560 * 2);
  u16*   qf    = (u16*)alloc((size_t)BATCH * 32 * MP * 8 * 2);
  u16*   kss   = (u16*)alloc((size_t)BATCH * AHOR * HD * 2);
  u16*   vss   = (u16*)alloc((size_t)BATCH * AHOR * HD * 2);
  u16*   opart = (u16*)alloc((size_t)BATCH * NSTR * MR * HD * 2);
  float* mrow  = (float*)alloc((size_t)BATCH * NSTR * MP * 4);
  float* lrow  = (float*)alloc((size_t)BATCH * NSTR * MP * 4);
  u16*   ao    = (u16*)alloc((size_t)256 * MP * 8 * 2);
  u16*   opp   = (u16*)alloc((size_t)8 * MP * 1024 * 2);
  u16*   mlpf  = (u16*)alloc((size_t)512 * MP * 8 * 2);
  u16*   mdp   = (u16*)alloc((size_t)8 * MP * 1024 * 2);
  unsigned* bar = (unsigned*)alloc(256);
  if (off > ws_size) return;

  hipMemsetAsync(bar, 0, 8, stream);

  k_prep<<<1, 256, 0, stream>>>(msk, ts, temb, offs, ropec, ropes);
  k_tproj<<<32, 256, 0, stream>>>(temb, Wti, bti, ttmp);
  k_tproj<<<32, 256, 0, stream>>>(ttmp, Wto, bto, cond);
  k_ada_part<<<dim3(3, 37, 4), 256, 0, stream>>>(cond, A1, A2, Af, adap);
  k_ada_red<<<444, 256, 0, stream>>>(adap, ada);
  k_hin<<<MR, 256, 0, stream>>>(xt, Wai, bai, h);
  k_resnorm0<<<128, 256, 0, stream>>>(h, ada + 0, ada + (size_t)1 * BATCH * HIDN, n1);

  k_layers<<<NBLK, 512, 0, stream>>>(pk, pv, msk, ropec, ropes,
                                     Wq, Wk, Wv, Wo, Wg, Wu, Wd, ada,
                                     h, h1, n1, n2, qkvp, qf, kss, vss,
                                     opart, mrow, lrow, ao, opp, mlpf, mdp, bar);

  k_out<<<50, 256, 0, stream>>>(n1, Wao, bao, (float*)d_out);
}

// Round 5
// 5558.469 us; speedup vs baseline: 2.4003x; 2.4003x over previous
//
#include <hip/hip_runtime.h>

typedef unsigned short u16;
typedef unsigned int   u32;
typedef __attribute__((ext_vector_type(8))) short bh8;
typedef __attribute__((ext_vector_type(4))) float f4;

constexpr int BATCH = 8, HIDN = 1024, NHEAD = 8, HD = 256, NLAY = 18, DMLP = 4096;
constexpr int AHOR = 50, ADIMN = 32, PFXN = 1037, SEQN = 1087, NSTR = 17, MR = 400, MP = 512;
constexpr float EPSV = 1e-6f, NEGV = -2.3819763e38f, QSCALE = 0.0625f;
constexpr int NBLK = 256;
constexpr size_t ADASL = (size_t)37 * 3 * BATCH * HIDN; // 909312

static __device__ __forceinline__ u16 f2bf(float x){
  union{float f; u32 u;} v; v.f = x;
  u32 r = (v.u + 0x7FFFu + ((v.u >> 16) & 1u)) >> 16;
  return (u16)r;
}
static __device__ __forceinline__ float bf2f(u16 u){
  union{u32 u; float f;} v; v.u = ((u32)u) << 16; return v.f;
}
static __device__ __forceinline__ u32 pack2(float a, float b){
  return (u32)f2bf(a) | ((u32)f2bf(b) << 16);
}
static __device__ __forceinline__ f4 MFMA(bh8 a, bh8 b, f4 c){
  return __builtin_amdgcn_mfma_f32_16x16x32_bf16(a, b, c, 0, 0, 0);
}
static __device__ __forceinline__ float siluf_(float x){ return x / (1.f + __expf(-x)); }
static __device__ __forceinline__ float geluf_(float x){
  float y = 0.7978845608028654f * (x + 0.044715f * x * x * x);
  float e = __expf(2.f * y);
  return 0.5f * x * (2.f - 2.f / (e + 1.f));
}

// -------- device-scope grid barrier, relaxed-spin + single acquire fence --------
// bar layout (u32): [g*32] 8 group arrive counters (128B apart), [256] group count, [320] generation
static __device__ __forceinline__ void gsync(unsigned* bar){
  __syncthreads();
  if (threadIdx.x == 0){
    unsigned* garr = bar + ((blockIdx.x >> 5) << 5);
    unsigned* gcnt = bar + 256;
    unsigned* gen  = bar + 320;
    unsigned g = __hip_atomic_load(gen, __ATOMIC_RELAXED, __HIP_MEMORY_SCOPE_AGENT);
    unsigned a = __hip_atomic_fetch_add(garr, 1u, __ATOMIC_RELEASE, __HIP_MEMORY_SCOPE_AGENT);
    if (a == 31u){
      __hip_atomic_store(garr, 0u, __ATOMIC_RELAXED, __HIP_MEMORY_SCOPE_AGENT);
      unsigned b2 = __hip_atomic_fetch_add(gcnt, 1u, __ATOMIC_ACQ_REL, __HIP_MEMORY_SCOPE_AGENT);
      if (b2 == 7u){
        __hip_atomic_store(gcnt, 0u, __ATOMIC_RELAXED, __HIP_MEMORY_SCOPE_AGENT);
        __hip_atomic_fetch_add(gen, 1u, __ATOMIC_ACQ_REL, __HIP_MEMORY_SCOPE_AGENT);
      }
    }
    while (__hip_atomic_load(gen, __ATOMIC_RELAXED, __HIP_MEMORY_SCOPE_AGENT) == g){
      __builtin_amdgcn_s_sleep(2);
    }
    __builtin_amdgcn_fence(__ATOMIC_ACQUIRE, "agent"); // one L1/L2 invalidate per block
  }
  __syncthreads();
}

// ---------------- prep: temb, offs, rope tables ----------------
__global__ void k_prep(const int* __restrict__ mask, const float* __restrict__ ts,
                       float* __restrict__ temb, int* __restrict__ offs,
                       float* __restrict__ ropec, float* __restrict__ ropes)
{
  int t = threadIdx.x;
  { // parallel mask popcount: 32 lanes per batch
    int b = t >> 5, l = t & 31;
    const int* mp = mask + b * PFXN;
    int s = 0;
    for (int k = l; k < PFXN; k += 32) s += (mp[k] != 0);
    #pragma unroll
    for (int off = 16; off >= 1; off >>= 1) s += __shfl_xor(s, off);
    if (l == 0) offs[b] = s;
  }
  for (int i = t; i < BATCH * 512; i += 256){
    int b = i >> 9, j = i & 511;
    float frac = (float)j * (1.0f / 511.0f);
    float period = 0.004f * __expf(frac * 6.907755278982137f); // ln(1000)
    float arg = (6.283185307179586f / period) * ts[b];
    float s, c; sincosf(arg, &s, &c);
    temb[b * HIDN + j] = s;
    temb[b * HIDN + 512 + j] = c;
  }
  __syncthreads();
  for (int i = t; i < BATCH * AHOR * 128; i += 256){
    int d = i & 127, bt = i >> 7, b = bt / AHOR, tt = bt % AHOR;
    float inv = __expf(-((float)d * (1.f / 128.f)) * 9.210340371976184f); // ln(10000)
    float arg = (float)(offs[b] + tt) * inv;
    float s, c; sincosf(arg, &s, &c);
    ropec[i] = c; ropes[i] = s;
  }
}

// ---------------- tiny M=8 GEMM (1024x1024) + silu ----------------
__global__ void k_tproj(const float* __restrict__ X, const float* __restrict__ W,
                        const float* __restrict__ bias, float* __restrict__ out)
{
  __shared__ float xs[BATCH * HIDN];
  __shared__ float red[BATCH][8][32];
  int t = threadIdx.x;
  for (int i = t; i < BATCH * HIDN; i += 256) xs[i] = X[i];
  __syncthreads();
  int c = t & 31, kp = t >> 5;
  int c0 = blockIdx.x * 32;
  float acc[BATCH];
  #pragma unroll
  for (int b = 0; b < BATCH; ++b) acc[b] = 0.f;
  for (int k = kp * 128; k < kp * 128 + 128; ++k){
    float w = W[(size_t)k * HIDN + c0 + c];
    #pragma unroll
    for (int b = 0; b < BATCH; ++b) acc[b] += xs[b * HIDN + k] * w;
  }
  #pragma unroll
  for (int b = 0; b < BATCH; ++b) red[b][kp][c] = acc[b];
  __syncthreads();
  int b2 = t >> 5, c2 = t & 31;
  float s = bias[c0 + c2];
  #pragma unroll
  for (int kp2 = 0; kp2 < 8; ++kp2) s += red[b2][kp2][c2];
  out[b2 * HIDN + c0 + c2] = siluf_(s);
}

// ---------------- ada partial: K-split x4, batched f4 loads ----------------
__global__ void k_ada_part(const float* __restrict__ cond, const float* __restrict__ A1,
                           const float* __restrict__ A2, const float* __restrict__ Af,
                           float* __restrict__ adap)
{
  __shared__ float cs[BATCH * 256];
  int t = threadIdx.x; // 256
  int y = blockIdx.y, ks = blockIdx.z;
  int k0 = ks * 256;
  for (int i = t; i < BATCH * 256; i += 256){
    int b = i >> 8, kk = i & 255;
    cs[i] = cond[b * HIDN + k0 + kk];
  }
  __syncthreads();
  const float* A = (y < NLAY) ? (A1 + (size_t)y * HIDN * 3072)
                  : (y < 2 * NLAY) ? (A2 + (size_t)(y - NLAY) * HIDN * 3072) : Af;
  int n = (blockIdx.x * 256 + t) * 4; // 0..3068
  f4 acc[BATCH];
  #pragma unroll
  for (int b = 0; b < BATCH; ++b) acc[b] = (f4){0.f,0.f,0.f,0.f};
  const float* ap = A + (size_t)k0 * 3072 + n;
  for (int kk = 0; kk < 256; kk += 8){
    f4 av[8];
    #pragma unroll
    for (int j = 0; j < 8; ++j) av[j] = *(const f4*)(ap + (size_t)(kk + j) * 3072);
    #pragma unroll
    for (int j = 0; j < 8; ++j){
      #pragma unroll
      for (int b = 0; b < BATCH; ++b) acc[b] += av[j] * cs[b * 256 + kk + j];
    }
  }
  int comp = n >> 10, nn = n & 1023;
  float* o = adap + (size_t)ks * ADASL + ((size_t)y * 3 + comp) * BATCH * HIDN + nn;
  #pragma unroll
  for (int b = 0; b < BATCH; ++b) *(f4*)(o + b * HIDN) = acc[b];
}

__global__ void k_ada_red(const float* __restrict__ adap, float* __restrict__ ada)
{
  size_t i = ((size_t)blockIdx.x * 256 + threadIdx.x) * 8;
  f4 a0 = {0,0,0,0}, a1 = {0,0,0,0};
  #pragma unroll
  for (int ks = 0; ks < 4; ++ks){
    const float* p = adap + (size_t)ks * ADASL + i;
    a0 += *(const f4*)p;
    a1 += *(const f4*)(p + 4);
  }
  *(f4*)(ada + i) = a0;
  *(f4*)(ada + i + 4) = a1;
}

// ---------------- h0 = x_t @ W_act_in + b ----------------
__global__ void k_hin(const float* __restrict__ xt, const float* __restrict__ W,
                      const float* __restrict__ bias, float* __restrict__ h)
{
  int r = blockIdx.x; // 0..399
  int t = threadIdx.x; int c0 = t * 4;
  __shared__ float xs[ADIMN];
  if (t < ADIMN) xs[t] = xt[r * ADIMN + t];
  __syncthreads();
  float a0 = bias[c0], a1 = bias[c0+1], a2 = bias[c0+2], a3 = bias[c0+3];
  for (int k = 0; k < ADIMN; ++k){
    float x = xs[k];
    const float* wp = W + k * HIDN + c0;
    a0 += x * wp[0]; a1 += x * wp[1]; a2 += x * wp[2]; a3 += x * wp[3];
  }
  float* hp = h + (size_t)r * HIDN + c0;
  hp[0] = a0; hp[1] = a1; hp[2] = a2; hp[3] = a3;
}

// ---------------- standalone RMS+AdaNorm (mode 0, prologue only) ----------------
__global__ void k_resnorm0(const float* __restrict__ base, const float* __restrict__ sc,
                           const float* __restrict__ sh, u16* __restrict__ fragA)
{
  __shared__ float redl[4];
  int t = threadIdx.x;
  int c = t * 4;
  for (int i = 0; i < 4; ++i){
    int r = blockIdx.x * 4 + i;
    bool live = (r < MR);
    float4 v = {0.f,0.f,0.f,0.f};
    int b = live ? (r / AHOR) : 0;
    if (live) v = *(const float4*)(base + (size_t)r * HIDN + c);
    float ss = v.x*v.x + v.y*v.y + v.z*v.z + v.w*v.w;
    #pragma unroll
    for (int off = 1; off < 64; off <<= 1) ss += __shfl_xor(ss, off);
    if ((t & 63) == 0) redl[t >> 6] = ss;
    __syncthreads();
    float tot = redl[0] + redl[1] + redl[2] + redl[3];
    __syncthreads();
    u16* dst = fragA + ((size_t)(c >> 3)) * MP * 8 + (size_t)r * 8 + (c & 7);
    ushort4 ov;
    if (live){
      float rstd = rsqrtf(tot * (1.0f / HIDN) + EPSV);
      const float4 scp = *(const float4*)(sc + b * HIDN + c);
      const float4 shp = *(const float4*)(sh + b * HIDN + c);
      ov.x = f2bf(v.x * rstd * (1.f + scp.x) + shp.x);
      ov.y = f2bf(v.y * rstd * (1.f + scp.y) + shp.y);
      ov.z = f2bf(v.z * rstd * (1.f + scp.z) + shp.z);
      ov.w = f2bf(v.w * rstd * (1.f + scp.w) + shp.w);
    } else {
      ov.x = ov.y = ov.z = ov.w = 0;
    }
    *(ushort4*)dst = ov;
  }
}

// ---------------- GEMM core 64-col: double-buffered LDS, depth-2 W prefetch ----------------
template<int NOUTER>
static __device__ __forceinline__ void gemm_core64(
    const u16* __restrict__ fa,
    const float* __restrict__ Wa, int cb0,
    const float* __restrict__ Wb, int cb1,
    int wN, int kc0, u16* lds, f4 acc[4][4])
{
  const int tid = threadIdx.x;
  const int lane = tid & 63, wave = tid >> 6;
  const int l15 = lane & 15, g = lane >> 4;
  const int wrow = wave * 64;
  const int sn = tid & 63, skb = (tid >> 6) * 8;
  const float* wbase = (sn < 32) ? (Wa + cb0 + sn) : (Wb + cb1 + (sn - 32));
  const size_t krow0 = (size_t)kc0 * 8 + skb;
  float pre[2][8];
  #pragma unroll
  for (int j = 0; j < 8; ++j) pre[0][j] = wbase[(krow0 + j) * wN];
  if (NOUTER > 1){
    #pragma unroll
    for (int j = 0; j < 8; ++j) pre[1][j] = wbase[(krow0 + 64 + j) * wN];
  }
  { u32* dst = (u32*)(lds + sn * 88 + skb);
    dst[0] = pack2(pre[0][0], pre[0][1]); dst[1] = pack2(pre[0][2], pre[0][3]);
    dst[2] = pack2(pre[0][4], pre[0][5]); dst[3] = pack2(pre[0][6], pre[0][7]); }
  __syncthreads();
  #pragma unroll
  for (int ko = 0; ko < NOUTER; ++ko){
    u16* ldsr = lds + (ko & 1) * (64 * 88);
    bh8 a[2][4];
    #pragma unroll
    for (int kk = 0; kk < 2; ++kk){
      int kcg = kc0 + ko * 8 + kk * 4 + g;
      const u16* ap = fa + ((size_t)kcg * MP + wrow + l15) * 8;
      #pragma unroll
      for (int mf = 0; mf < 4; ++mf) a[kk][mf] = *(const bh8*)(ap + mf * 128);
    }
    if (ko + 2 < NOUTER){
      #pragma unroll
      for (int j = 0; j < 8; ++j) pre[ko & 1][j] = wbase[(krow0 + (size_t)(ko + 2) * 64 + j) * wN];
    }
    #pragma unroll
    for (int kk = 0; kk < 2; ++kk){
      bh8 bb[4];
      #pragma unroll
      for (int nf = 0; nf < 4; ++nf) bb[nf] = *(const bh8*)(ldsr + (nf * 16 + l15) * 88 + kk * 32 + g * 8);
      #pragma unroll
      for (int mf = 0; mf < 4; ++mf)
        #pragma unroll
        for (int nf = 0; nf < 4; ++nf)
          acc[mf][nf] = MFMA(a[kk][mf], bb[nf], acc[mf][nf]);
    }
    if (ko + 1 < NOUTER){
      u16* ldsw = lds + ((ko + 1) & 1) * (64 * 88);
      u32* dst = (u32*)(ldsw + sn * 88 + skb);
      const float* p = pre[(ko + 1) & 1];
      dst[0] = pack2(p[0], p[1]); dst[1] = pack2(p[2], p[3]);
      dst[2] = pack2(p[4], p[5]); dst[3] = pack2(p[6], p[7]);
      __syncthreads();
    }
  }
}

// ---------------- GEMM core 32-col wide-K: 128 k/iter, double-buffered ----------------
template<int NOUTER>
static __device__ __forceinline__ void gemm_core32w(
    const u16* __restrict__ fa,
    const float* __restrict__ Wa, int cb0,
    const float* __restrict__ Wb, int cb1,
    int wN, u16* lds, f4 acc[4][2])
{
  const int tid = threadIdx.x;
  const int lane = tid & 63, wave = tid >> 6;
  const int l15 = lane & 15, g = lane >> 4;
  const int wrow = wave * 64;
  const int sc = tid & 31, kq = tid >> 5;
  const int kb = kq * 8;
  const float* wbase = (sc < 16) ? (Wa + cb0 + sc) : (Wb + cb1 + (sc - 16));
  float pre[2][8];
  #pragma unroll
  for (int j = 0; j < 8; ++j) pre[0][j] = wbase[(size_t)(kb + j) * wN];
  if (NOUTER > 1){
    #pragma unroll
    for (int j = 0; j < 8; ++j) pre[1][j] = wbase[(size_t)(128 + kb + j) * wN];
  }
  { u32* dst = (u32*)(lds + sc * 136 + kb);
    dst[0] = pack2(pre[0][0], pre[0][1]); dst[1] = pack2(pre[0][2], pre[0][3]);
    dst[2] = pack2(pre[0][4], pre[0][5]); dst[3] = pack2(pre[0][6], pre[0][7]); }
  __syncthreads();
  #pragma unroll
  for (int ko = 0; ko < NOUTER; ++ko){
    u16* ldsr = lds + (ko & 1) * (32 * 136);
    bh8 a[2][4];
    #pragma unroll
    for (int kk = 0; kk < 2; ++kk){
      int kcg = ko * 16 + kk * 4 + g;
      const u16* ap = fa + ((size_t)kcg * MP + wrow + l15) * 8;
      #pragma unroll
      for (int mf = 0; mf < 4; ++mf) a[kk][mf] = *(const bh8*)(ap + mf * 128);
    }
    if (ko + 2 < NOUTER){
      #pragma unroll
      for (int j = 0; j < 8; ++j) pre[ko & 1][j] = wbase[(size_t)((ko + 2) * 128 + kb + j) * wN];
    }
    #pragma unroll
    for (int kk = 0; kk < 2; ++kk){
      bh8 bb[2];
      #pragma unroll
      for (int nf = 0; nf < 2; ++nf) bb[nf] = *(const bh8*)(ldsr + (nf * 16 + l15) * 136 + kk * 32 + g * 8);
      #pragma unroll
      for (int mf = 0; mf < 4; ++mf){
        acc[mf][0] = MFMA(a[kk][mf], bb[0], acc[mf][0]);
        acc[mf][1] = MFMA(a[kk][mf], bb[1], acc[mf][1]);
      }
    }
    #pragma unroll
    for (int kk = 2; kk < 4; ++kk){
      int kcg = ko * 16 + kk * 4 + g;
      const u16* ap = fa + ((size_t)kcg * MP + wrow + l15) * 8;
      #pragma unroll
      for (int mf = 0; mf < 4; ++mf) a[kk - 2][mf] = *(const bh8*)(ap + mf * 128);
    }
    #pragma unroll
    for (int kk = 2; kk < 4; ++kk){
      bh8 bb[2];
      #pragma unroll
      for (int nf = 0; nf < 2; ++nf) bb[nf] = *(const bh8*)(ldsr + (nf * 16 + l15) * 136 + kk * 32 + g * 8);
      #pragma unroll
      for (int mf = 0; mf < 4; ++mf){
        acc[mf][0] = MFMA(a[kk - 2][mf], bb[0], acc[mf][0]);
        acc[mf][1] = MFMA(a[kk - 2][mf], bb[1], acc[mf][1]);
      }
    }
    if (ko + 1 < NOUTER){
      u16* ldsw = lds + ((ko + 1) & 1) * (32 * 136);
      u32* dst = (u32*)(ldsw + sc * 136 + kb);
      const float* p = pre[(ko + 1) & 1];
      dst[0] = pack2(p[0], p[1]); dst[1] = pack2(p[2], p[3]);
      dst[2] = pack2(p[4], p[5]); dst[3] = pack2(p[6], p[7]);
      __syncthreads();
    }
  }
}

// ================= mega-kernel phase bodies (512 threads each) =================

static __device__ __forceinline__ void ph_qkv(int task,
    const u16* n1, const float* Wq, const float* Wk, const float* Wv,
    u16* qkvp, u16* lds)
{
  int bx = task % 40, ksl = task / 40;
  const float* W; int wN, cb0, colbase;
  if (bx < 32){ W = Wq; wN = NHEAD * HD; cb0 = bx * 64; colbase = bx * 64; }
  else if (bx < 36){ W = Wk; wN = HD; cb0 = (bx - 32) * 64; colbase = 2048 + cb0; }
  else { W = Wv; wN = HD; cb0 = (bx - 36) * 64; colbase = 2304 + cb0; }
  f4 acc[4][4];
  #pragma unroll
  for (int i = 0; i < 4; ++i)
    #pragma unroll
    for (int j = 0; j < 4; ++j) acc[i][j] = (f4){0.f, 0.f, 0.f, 0.f};
  gemm_core64<4>(n1, W, cb0, W, cb0 + 32, wN, ksl * 32, lds, acc);
  int tid = threadIdx.x, lane = tid & 63, wave = tid >> 6, l15 = lane & 15, g = lane >> 4;
  int wrow = wave * 64;
  #pragma unroll
  for (int mf = 0; mf < 4; ++mf)
    #pragma unroll
    for (int r = 0; r < 4; ++r){
      int row = wrow + mf * 16 + 4 * g + r;
      #pragma unroll
      for (int nf = 0; nf < 4; ++nf)
        qkvp[((size_t)ksl * MP + row) * 2560 + colbase + nf * 16 + l15] = f2bf(acc[mf][nf][r]);
    }
}

static __device__ __forceinline__ void ph_rope(int task,
    const u16* qkvp, const float* ropec, const float* ropes,
    u16* qf, u16* ks, u16* vs)
{
  int tid = threadIdx.x;
  int rl = tid & 255, rr = tid >> 8;
  int r = task * 2 + rr; // 0..399
  int b = r / AHOR, tt = r - b * AHOR;
  const u16* base = qkvp + (size_t)r * 2560;
  const size_t SL = (size_t)MP * 2560;
  #pragma unroll
  for (int i = 0; i < 4; ++i){
    int idx = rl + 256 * i; int head = idx >> 7, dA = idx & 127;
    int cL = head * 256 + dA, cH = cL + 128;
    float lo = bf2f(base[cL]) + bf2f(base[SL + cL]) + bf2f(base[2 * SL + cL]) + bf2f(base[3 * SL + cL]);
    float hi = bf2f(base[cH]) + bf2f(base[SL + cH]) + bf2f(base[2 * SL + cH]) + bf2f(base[3 * SL + cH]);
    float cz = ropec[(size_t)r * 128 + dA], sz = ropes[(size_t)r * 128 + dA];
    float oA = (lo * cz - hi * sz) * QSCALE;
    float oB = (hi * cz + lo * sz) * QSCALE;
    int rowp = head * AHOR + tt;
    int dB = dA + 128;
    qf[((size_t)(b * 32 + (dA >> 3))) * MP * 8 + (size_t)rowp * 8 + (dA & 7)] = f2bf(oA);
    qf[((size_t)(b * 32 + (dB >> 3))) * MP * 8 + (size_t)rowp * 8 + (dB & 7)] = f2bf(oB);
  }
  if (rl < 128){
    int dA = rl, cL = 2048 + dA, cH = cL + 128;
    float lo = bf2f(base[cL]) + bf2f(base[SL + cL]) + bf2f(base[2 * SL + cL]) + bf2f(base[3 * SL + cL]);
    float hi = bf2f(base[cH]) + bf2f(base[SL + cH]) + bf2f(base[2 * SL + cH]) + bf2f(base[3 * SL + cH]);
    float cz = ropec[(size_t)r * 128 + dA], sz = ropes[(size_t)r * 128 + dA];
    ks[(size_t)r * HD + dA] = f2bf(lo * cz - hi * sz);
    ks[(size_t)r * HD + dA + 128] = f2bf(hi * cz + lo * sz);
  }
  {
    int c = 2304 + rl;
    float v = bf2f(base[c]) + bf2f(base[SL + c]) + bf2f(base[2 * SL + c]) + bf2f(base[3 * SL + c]);
    vs[(size_t)r * HD + rl] = f2bf(v);
  }
}

static __device__ __forceinline__ void ph_attn(int task, int layer,
    const u16* qf, const u16* kss, const u16* vss,
    const float* pk, const float* pv, const int* mask,
    u16* opart, float* mrow, float* lrow, u16* kv, u16* plds)
{
  __syncthreads(); // protect smem reuse across phases
  int s = task % NSTR, b = task / NSTR;
  int tid = threadIdx.x, lane = tid & 63, wave = tid >> 6, l15 = lane & 15, g = lane >> 4;
  int wrow = wave * 64;
  int key = tid >> 3, dblk = (tid & 7) * 32;
  int kg = s * 64 + key;
  { // stage K tile (bf16) direct to LDS
    u32* dst = (u32*)(kv + key * 264 + dblk);
    if (kg < PFXN){
      const float4* src = (const float4*)(pk + (((size_t)b * NLAY + layer) * PFXN + kg) * HD + dblk);
      #pragma unroll
      for (int j = 0; j < 8; ++j){ float4 v = src[j]; dst[2*j] = pack2(v.x, v.y); dst[2*j+1] = pack2(v.z, v.w); }
    } else if (kg < SEQN){
      const u32* src = (const u32*)(kss + ((size_t)b * AHOR + (kg - PFXN)) * HD + dblk);
      #pragma unroll
      for (int j = 0; j < 16; ++j) dst[j] = src[j];
    } else {
      #pragma unroll
      for (int j = 0; j < 16; ++j) dst[j] = 0;
    }
  }
  // prefetch V tile into registers
  float vreg[32];
  if (kg < PFXN){
    const float4* src = (const float4*)(pv + (((size_t)b * NLAY + layer) * PFXN + kg) * HD + dblk);
    #pragma unroll
    for (int j = 0; j < 8; ++j){ float4 v = src[j]; vreg[4*j] = v.x; vreg[4*j+1] = v.y; vreg[4*j+2] = v.z; vreg[4*j+3] = v.w; }
  } else if (kg < SEQN){
    const u32* src = (const u32*)(vss + ((size_t)b * AHOR + (kg - PFXN)) * HD + dblk);
    #pragma unroll
    for (int j = 0; j < 16; ++j){ u32 u = src[j]; vreg[2*j] = bf2f((u16)(u & 0xFFFF)); vreg[2*j+1] = bf2f((u16)(u >> 16)); }
  } else {
    #pragma unroll
    for (int j = 0; j < 32; ++j) vreg[j] = 0.f;
  }
  bool valid[4];
  #pragma unroll
  for (int nf = 0; nf < 4; ++nf){
    int kgc = s * 64 + nf * 16 + l15;
    valid[nf] = (kgc < PFXN) ? (mask[b * PFXN + kgc] != 0) : (kgc < SEQN);
  }
  __syncthreads();
  // S = (Q*scale) K^T
  f4 acc[4][4];
  #pragma unroll
  for (int i = 0; i < 4; ++i)
    #pragma unroll
    for (int j = 0; j < 4; ++j) acc[i][j] = (f4){0.f,0.f,0.f,0.f};
  const u16* qb = qf + (size_t)b * 32 * MP * 8;
  #pragma unroll
  for (int ko = 0; ko < 4; ++ko)
    #pragma unroll
    for (int kk = 0; kk < 2; ++kk){
      int kc = ko * 8 + kk * 4 + g;
      bh8 a[4], bb[4];
      const u16* ap = qb + ((size_t)kc * MP + wrow + l15) * 8;
      #pragma unroll
      for (int mf = 0; mf < 4; ++mf) a[mf] = *(const bh8*)(ap + mf * 128);
      #pragma unroll
      for (int nf = 0; nf < 4; ++nf) bb[nf] = *(const bh8*)(kv + (nf * 16 + l15) * 264 + ko * 64 + kk * 32 + g * 8);
      #pragma unroll
      for (int mf = 0; mf < 4; ++mf)
        #pragma unroll
        for (int nf = 0; nf < 4; ++nf) acc[mf][nf] = MFMA(a[mf], bb[nf], acc[mf][nf]);
    }
  #pragma unroll
  for (int nf = 0; nf < 4; ++nf) if (!valid[nf]){
    #pragma unroll
    for (int mf = 0; mf < 4; ++mf){
      acc[mf][nf][0] = NEGV; acc[mf][nf][1] = NEGV; acc[mf][nf][2] = NEGV; acc[mf][nf][3] = NEGV;
    }
  }
  // per-strip softmax
  #pragma unroll
  for (int mf = 0; mf < 4; ++mf)
    #pragma unroll
    for (int r = 0; r < 4; ++r){
      float m0 = fmaxf(fmaxf(acc[mf][0][r], acc[mf][1][r]), fmaxf(acc[mf][2][r], acc[mf][3][r]));
      #pragma unroll
      for (int off = 1; off < 16; off <<= 1) m0 = fmaxf(m0, __shfl_xor(m0, off));
      int row = wrow + mf * 16 + 4 * g + r;
      float sum = 0.f;
      #pragma unroll
      for (int nf = 0; nf < 4; ++nf){
        float p = __expf(acc[mf][nf][r] - m0);
        sum += p;
        plds[row * 72 + nf * 16 + l15] = f2bf(p);
      }
      #pragma unroll
      for (int off = 1; off < 16; off <<= 1) sum += __shfl_xor(sum, off);
      if (l15 == 0){
        mrow[((size_t)b * NSTR + s) * MP + row] = m0;
        lrow[((size_t)b * NSTR + s) * MP + row] = sum;
      }
    }
  __syncthreads();
  { // write V^T from regs with skewed layout
    #pragma unroll
    for (int j = 0; j < 32; ++j){
      int d = dblk + j;
      kv[d * 88 + ((d >> 5) & 3) * 8 + key] = f2bf(vreg[j]);
    }
  }
  __syncthreads();
  // O_part = P V
  #pragma unroll
  for (int dc = 0; dc < 4; ++dc){
    f4 oc[4][4];
    #pragma unroll
    for (int i = 0; i < 4; ++i)
      #pragma unroll
      for (int j = 0; j < 4; ++j) oc[i][j] = (f4){0.f,0.f,0.f,0.f};
    #pragma unroll
    for (int kk = 0; kk < 2; ++kk){
      bh8 a[4], bb[4];
      #pragma unroll
      for (int mf = 0; mf < 4; ++mf) a[mf] = *(const bh8*)(plds + (wrow + mf * 16 + l15) * 72 + kk * 32 + g * 8);
      #pragma unroll
      for (int nf = 0; nf < 4; ++nf){
        int dcol = dc * 64 + nf * 16 + l15;
        bb[nf] = *(const bh8*)(kv + dcol * 88 + ((dcol >> 5) & 3) * 8 + kk * 32 + g * 8);
      }
      #pragma unroll
      for (int mf = 0; mf < 4; ++mf)
        #pragma unroll
        for (int nf = 0; nf < 4; ++nf) oc[mf][nf] = MFMA(a[mf], bb[nf], oc[mf][nf]);
    }
    #pragma unroll
    for (int mf = 0; mf < 4; ++mf)
      #pragma unroll
      for (int r = 0; r < 4; ++r){
        int row = wrow + mf * 16 + 4 * g + r;
        if (row < MR){
          #pragma unroll
          for (int nf = 0; nf < 4; ++nf){
            int d = dc * 64 + nf * 16 + l15;
            opart[(((size_t)b * NSTR + s) * MR + row) * HD + d] = f2bf(oc[mf][nf][r]);
          }
        }
      }
  }
}

static __device__ __forceinline__ void ph_comb(int task,
    const u16* opart, const float* mrow, const float* lrow, u16* ao)
{
  int rg = task % 25, b = task / 25;
  int tid = threadIdx.x;
  int d = tid & 255, half = tid >> 8;
  int r0 = rg * 16 + half * 8;
  for (int i = 0; i < 8; ++i){
    int row = r0 + i;
    float M = -3.0e38f;
    for (int s2 = 0; s2 < NSTR; ++s2) M = fmaxf(M, mrow[((size_t)b * NSTR + s2) * MP + row]);
    float L = 0.f, o = 0.f;
    for (int s2 = 0; s2 < NSTR; ++s2){
      float w = __expf(mrow[((size_t)b * NSTR + s2) * MP + row] - M);
      L += w * lrow[((size_t)b * NSTR + s2) * MP + row];
      o += w * bf2f(opart[(((size_t)b * NSTR + s2) * MR + row) * HD + d]);
    }
    float val = o / L;
    int h = row / AHOR, tt = row - h * AHOR;
    int col = h * HD + d;
    int rgl = b * AHOR + tt;
    ao[((size_t)(col >> 3)) * MP * 8 + (size_t)rgl * 8 + (col & 7)] = f2bf(val);
  }
}

template<int NOUTER>
static __device__ __forceinline__ void ph_gemm(int task,
    const u16* fa, const float* W, int wN, int kcPerSlice, u16* outp, u16* lds)
{
  int nx = task & 15, ksl = task >> 4;
  int n0 = nx * 64;
  f4 acc[4][4];
  #pragma unroll
  for (int i = 0; i < 4; ++i)
    #pragma unroll
    for (int j = 0; j < 4; ++j) acc[i][j] = (f4){0.f,0.f,0.f,0.f};
  gemm_core64<NOUTER>(fa, W, n0, W, n0 + 32, wN, ksl * kcPerSlice, lds, acc);
  int tid = threadIdx.x, lane = tid & 63, wave = tid >> 6, l15 = lane & 15, g = lane >> 4;
  int wrow = wave * 64;
  #pragma unroll
  for (int mf = 0; mf < 4; ++mf)
    #pragma unroll
    for (int r = 0; r < 4; ++r){
      int row = wrow + mf * 16 + 4 * g + r;
      #pragma unroll
      for (int nf = 0; nf < 4; ++nf)
        outp[((size_t)ksl * MP + row) * 1024 + n0 + nf * 16 + l15] = f2bf(acc[mf][nf][r]);
    }
}

static __device__ __forceinline__ void ph_mlpup(int task,
    const u16* n2, const float* Wg, const float* Wu, u16* mlpf, u16* lds)
{
  int n0 = task * 16;
  f4 acc[4][2];
  #pragma unroll
  for (int i = 0; i < 4; ++i)
    #pragma unroll
    for (int j = 0; j < 2; ++j) acc[i][j] = (f4){0.f,0.f,0.f,0.f};
  gemm_core32w<8>(n2, Wg, n0, Wu, n0, DMLP, lds, acc);
  int tid = threadIdx.x, lane = tid & 63, wave = tid >> 6, l15 = lane & 15, g = lane >> 4;
  int wrow = wave * 64;
  #pragma unroll
  for (int mf = 0; mf < 4; ++mf)
    #pragma unroll
    for (int r = 0; r < 4; ++r){
      int row = wrow + mf * 16 + 4 * g + r;
      int col = n0 + l15;
      float gg = acc[mf][0][r], uu = acc[mf][1][r];
      float act = geluf_(gg) * uu;
      mlpf[((size_t)(col >> 3)) * MP * 8 + (size_t)row * 8 + (col & 7)] = f2bf(act);
    }
}

static __device__ __forceinline__ void ph_resnorm(int task, int np,
    const float* base, const u16* parts, const float* gate, const float* sc,
    const float* sh, float* outres, u16* fragA, float* redl)
{
  int tid = threadIdx.x;
  int tl = tid & 255, sub = tid >> 8;
  int c = tl * 4;
  int wv = tid >> 6;
  for (int i = 0; i < 2; ++i){
    int r = task * 4 + sub * 2 + i;
    bool live = (r < MR);
    float4 v = {0.f,0.f,0.f,0.f};
    int b = live ? (r / AHOR) : 0;
    if (live){
      v = *(const float4*)(base + (size_t)r * HIDN + c);
      float s0 = 0, s1 = 0, s2 = 0, s3 = 0;
      #pragma unroll 4
      for (int p = 0; p < np; ++p){
        ushort4 u4 = *(const ushort4*)(parts + ((size_t)p * MP + r) * HIDN + c);
        s0 += bf2f(u4.x); s1 += bf2f(u4.y); s2 += bf2f(u4.z); s3 += bf2f(u4.w);
      }
      float4 gp = *(const float4*)(gate + b * HIDN + c);
      v.x += gp.x * s0; v.y += gp.y * s1; v.z += gp.z * s2; v.w += gp.w * s3;
      *(float4*)(outres + (size_t)r * HIDN + c) = v;
    }
    float ss = v.x*v.x + v.y*v.y + v.z*v.z + v.w*v.w;
    #pragma unroll
    for (int off = 1; off < 64; off <<= 1) ss += __shfl_xor(ss, off);
    if ((tid & 63) == 0) redl[wv] = ss;
    __syncthreads();
    float tot = redl[sub * 4] + redl[sub * 4 + 1] + redl[sub * 4 + 2] + redl[sub * 4 + 3];
    __syncthreads();
    u16* dst = fragA + ((size_t)(c >> 3)) * MP * 8 + (size_t)r * 8 + (c & 7);
    ushort4 ov;
    if (live){
      float rstd = rsqrtf(tot * (1.0f / HIDN) + EPSV);
      const float4 scp = *(const float4*)(sc + b * HIDN + c);
      const float4 shp = *(const float4*)(sh + b * HIDN + c);
      ov.x = f2bf(v.x * rstd * (1.f + scp.x) + shp.x);
      ov.y = f2bf(v.y * rstd * (1.f + scp.y) + shp.y);
      ov.z = f2bf(v.z * rstd * (1.f + scp.z) + shp.z);
      ov.w = f2bf(v.w * rstd * (1.f + scp.w) + shp.w);
    } else {
      ov.x = ov.y = ov.z = ov.w = 0;
    }
    *(ushort4*)dst = ov;
  }
}

// ================= the persistent 18-layer mega-kernel =================
__global__ __launch_bounds__(512, 2) void k_layers(
    const float* __restrict__ pk, const float* __restrict__ pv, const int* __restrict__ msk,
    const float* __restrict__ ropec, const float* __restrict__ ropes,
    const float* __restrict__ Wq, const float* __restrict__ Wk, const float* __restrict__ Wv,
    const float* __restrict__ Wo, const float* __restrict__ Wg, const float* __restrict__ Wu,
    const float* __restrict__ Wd, const float* __restrict__ ada,
    float* h, float* h1, u16* n1, u16* n2,
    u16* qkvp, u16* qf, u16* kss, u16* vss,
    u16* opart, float* mrow, float* lrow, u16* ao,
    u16* opp, u16* mlpf, u16* mdp, unsigned* bar)
{
  __shared__ u16 smem[256 * 88 + 512 * 72]; // attn: kv + plds; gemms use prefix
  __shared__ float redl[8];
  u16* kv = smem;
  u16* plds = smem + 256 * 88;
  const int bid = blockIdx.x, G = gridDim.x;

  for (int l = 0; l < NLAY; ++l){
    const float* Wq_l = Wq + (size_t)l * HIDN * NHEAD * HD;
    const float* Wk_l = Wk + (size_t)l * HIDN * HD;
    const float* Wv_l = Wv + (size_t)l * HIDN * HD;
    const float* Wo_l = Wo + (size_t)l * 2048 * 1024;
    const float* Wg_l = Wg + (size_t)l * HIDN * DMLP;
    const float* Wu_l = Wu + (size_t)l * HIDN * DMLP;
    const float* Wd_l = Wd + (size_t)l * DMLP * 1024;
    const float* g1  = ada + ((size_t)l * 3 + 2) * BATCH * HIDN;
    const float* sc2 = ada + ((size_t)(NLAY + l) * 3 + 0) * BATCH * HIDN;
    const float* sh2 = ada + ((size_t)(NLAY + l) * 3 + 1) * BATCH * HIDN;
    const float* g2  = ada + ((size_t)(NLAY + l) * 3 + 2) * BATCH * HIDN;
    int ny = (l < NLAY - 1) ? (l + 1) : 36;
    const float* nsc = ada + ((size_t)ny * 3 + 0) * BATCH * HIDN;
    const float* nsh = ada + ((size_t)ny * 3 + 1) * BATCH * HIDN;

    for (int t = bid; t < 160; t += G) ph_qkv(t, n1, Wq_l, Wk_l, Wv_l, qkvp, smem);
    gsync(bar);
    for (int t = bid; t < 200; t += G) ph_rope(t, qkvp, ropec, ropes, qf, kss, vss);
    gsync(bar);
    for (int t = bid; t < NSTR * BATCH; t += G) ph_attn(t, l, qf, kss, vss, pk, pv, msk, opart, mrow, lrow, kv, plds);
    gsync(bar);
    for (int t = bid; t < 200; t += G) ph_comb(t, opart, mrow, lrow, ao);
    gsync(bar);
    for (int t = bid; t < 128; t += G) ph_gemm<4>(t, ao, Wo_l, 1024, 32, opp, smem);
    gsync(bar);
    for (int t = bid; t < 128; t += G) ph_resnorm(t, 8, h, opp, g1, sc2, sh2, h1, n2, redl);
    gsync(bar);
    for (int t = bid; t < 256; t += G) ph_mlpup(t, n2, Wg_l, Wu_l, mlpf, smem);
    gsync(bar);
    for (int t = bid; t < 128; t += G) ph_gemm<8>(t, mlpf, Wd_l, 1024, 64, mdp, smem);
    gsync(bar);
    for (int t = bid; t < 128; t += G) ph_resnorm(t, 8, h1, mdp, g2, nsc, nsh, h, n1, redl);
    gsync(bar);
  }
}

// ---------------- final: out = nf @ W_act_out + b ----------------
__global__ void k_out(const u16* __restrict__ nfr, const float* __restrict__ W,
                      const float* __restrict__ bias, float* __restrict__ out)
{
  int t = threadIdx.x;
  int row = blockIdx.x * 8 + (t >> 5);
  int c = t & 31;
  float acc = bias[c];
  for (int k = 0; k < HIDN; ++k)
    acc += bf2f(nfr[((size_t)(k >> 3)) * MP * 8 + (size_t)row * 8 + (k & 7)]) * W[k * ADIMN + c];
  out[row * ADIMN + c] = acc;
}

extern "C" void kernel_launch(void* const* d_in, const int* in_sizes, int n_in,
                              void* d_out, int out_size, void* d_ws, size_t ws_size,
                              hipStream_t stream)
{
  const float* pk  = (const float*)d_in[0];
  const float* pv  = (const float*)d_in[1];
  const int*   msk = (const int*)d_in[2];
  const float* xt  = (const float*)d_in[3];
  const float* ts  = (const float*)d_in[4];
  const float* Wq  = (const float*)d_in[5];
  const float* Wk  = (const float*)d_in[6];
  const float* Wv  = (const float*)d_in[7];
  const float* Wo  = (const float*)d_in[8];
  const float* Wg  = (const float*)d_in[9];
  const float* Wu  = (const float*)d_in[10];
  const float* Wd  = (const float*)d_in[11];
  const float* A1  = (const float*)d_in[12];
  const float* A2  = (const float*)d_in[13];
  const float* Af  = (const float*)d_in[14];
  const float* Wai = (const float*)d_in[15];
  const float* bai = (const float*)d_in[16];
  const float* Wao = (const float*)d_in[17];
  const float* bao = (const float*)d_in[18];
  const float* Wti = (const float*)d_in[19];
  const float* bti = (const float*)d_in[20];
  const float* Wto = (const float*)d_in[21];
  const float* bto = (const float*)d_in[22];

  char* w = (char*)d_ws;
  size_t off = 0;
  auto alloc = [&](size_t bytes) -> char* {
    char* p = w + off; off += (bytes + 255) & ~(size_t)255; return p;
  };
  float* temb  = (float*)alloc((size_t)BATCH * HIDN * 4);
  float* ttmp  = (float*)alloc((size_t)BATCH * HIDN * 4);
  float* cond  = (float*)alloc((size_t)BATCH * HIDN * 4);
  int*   offs  = (int*)alloc(BATCH * 4);
  float* ropec = (float*)alloc((size_t)BATCH * AHOR * 128 * 4);
  float* ropes = (float*)alloc((size_t)BATCH * AHOR * 128 * 4);
  float* ada   = (float*)alloc(ADASL * 4);
  float* adap  = (float*)alloc(4 * ADASL * 4);
  float* h     = (float*)alloc((size_t)MR * HIDN * 4);
  float* h1    = (float*)alloc((size_t)MR * HIDN * 4);
  u16*   n1    = (u16*)alloc((size_t)128 * MP * 8 * 2);
  u16*   n2    = (u16*)alloc((size_t)128 * MP * 8 * 2);
  u16*   qkvp  = (u16*)alloc((size_t)4 * MP * 2560 * 2);
  u16*   qf    = (u16*)alloc((size_t)BATCH * 32 * MP * 8 * 2);
  u16*   kss   = (u16*)alloc((size_t)BATCH * AHOR * HD * 2);
  u16*   vss   = (u16*)alloc((size_t)BATCH * AHOR * HD * 2);
  u16*   opart = (u16*)alloc((size_t)BATCH * NSTR * MR * HD * 2);
  float* mrow  = (float*)alloc((size_t)BATCH * NSTR * MP * 4);
  float* lrow  = (float*)alloc((size_t)BATCH * NSTR * MP * 4);
  u16*   ao    = (u16*)alloc((size_t)256 * MP * 8 * 2);
  u16*   opp   = (u16*)alloc((size_t)8 * MP * 1024 * 2);
  u16*   mlpf  = (u16*)alloc((size_t)512 * MP * 8 * 2);
  u16*   mdp   = (u16*)alloc((size_t)8 * MP * 1024 * 2);
  unsigned* bar = (unsigned*)alloc(4096);
  if (off > ws_size) return;

  hipMemsetAsync(bar, 0, 4096, stream);

  k_prep<<<1, 256, 0, stream>>>(msk, ts, temb, offs, ropec, ropes);
  k_tproj<<<32, 256, 0, stream>>>(temb, Wti, bti, ttmp);
  k_tproj<<<32, 256, 0, stream>>>(ttmp, Wto, bto, cond);
  k_ada_part<<<dim3(3, 37, 4), 256, 0, stream>>>(cond, A1, A2, Af, adap);
  k_ada_red<<<444, 256, 0, stream>>>(adap, ada);
  k_hin<<<MR, 256, 0, stream>>>(xt, Wai, bai, h);
  k_resnorm0<<<128, 256, 0, stream>>>(h, ada + 0, ada + (size_t)1 * BATCH * HIDN, n1);

  k_layers<<<NBLK, 512, 0, stream>>>(pk, pv, msk, ropec, ropes,
                                     Wq, Wk, Wv, Wo, Wg, Wu, Wd, ada,
                                     h, h1, n1, n2, qkvp, qf, kss, vss,
                                     opart, mrow, lrow, ao, opp, mlpf, mdp, bar);

  k_out<<<50, 256, 0, stream>>>(n1, Wao, bao, (float*)d_out);
}

// Round 6
// 5170.694 us; speedup vs baseline: 2.5803x; 1.0750x over previous
//
#include <hip/hip_runtime.h>

typedef unsigned short u16;
typedef unsigned int   u32;
typedef __attribute__((ext_vector_type(8))) short bh8;
typedef __attribute__((ext_vector_type(4))) float f4;

constexpr int BATCH = 8, HIDN = 1024, NHEAD = 8, HD = 256, NLAY = 18, DMLP = 4096;
constexpr int AHOR = 50, ADIMN = 32, PFXN = 1037, SEQN = 1087, NSTR = 17, MR = 400, MP = 512;
constexpr float EPSV = 1e-6f, NEGV = -2.3819763e38f, QSCALE = 0.0625f;
constexpr int NBLK = 256;
constexpr size_t ADASL = (size_t)37 * 3 * BATCH * HIDN; // 909312

static __device__ __forceinline__ u16 f2bf(float x){
  union{float f; u32 u;} v; v.f = x;
  u32 r = (v.u + 0x7FFFu + ((v.u >> 16) & 1u)) >> 16;
  return (u16)r;
}
static __device__ __forceinline__ float bf2f(u16 u){
  union{u32 u; float f;} v; v.u = ((u32)u) << 16; return v.f;
}
static __device__ __forceinline__ u32 pack2(float a, float b){
  return (u32)f2bf(a) | ((u32)f2bf(b) << 16);
}
static __device__ __forceinline__ f4 MFMA(bh8 a, bh8 b, f4 c){
  return __builtin_amdgcn_mfma_f32_16x16x32_bf16(a, b, c, 0, 0, 0);
}
static __device__ __forceinline__ float siluf_(float x){ return x / (1.f + __expf(-x)); }
static __device__ __forceinline__ float geluf_(float x){
  float y = 0.7978845608028654f * (x + 0.044715f * x * x * x);
  float e = __expf(2.f * y);
  return 0.5f * x * (2.f - 2.f / (e + 1.f));
}

static __device__ __forceinline__ int xcc_id(){
  unsigned v;
  asm volatile("s_getreg_b32 %0, hwreg(HW_REG_XCC_ID)" : "=s"(v));
  return (int)(v & 7u);
}

// -------- device barrier: XCD-leader release (8 wbl2, parallel) + relaxed spin --------
// bar: [x*32] per-XCD monotonic arrive counters (128B apart), [256] gcnt, [288] gen (all monotonic)
static __device__ __forceinline__ void gsync(unsigned* bar, int xcc){
  __syncthreads(); // compiler emits s_waitcnt vmcnt(0) before s_barrier -> all waves' stores at L2
  if (threadIdx.x == 0){
    unsigned* xarr = bar + (xcc << 5);
    unsigned* gcnt = bar + 256;
    unsigned* gen  = bar + 288;
    unsigned g = __hip_atomic_load(gen, __ATOMIC_RELAXED, __HIP_MEMORY_SCOPE_AGENT);
    unsigned a = __hip_atomic_fetch_add(xarr, 1u, __ATOMIC_RELAXED, __HIP_MEMORY_SCOPE_AGENT);
    if ((a & 31u) == 31u){ // last arriver on this XCD
      __builtin_amdgcn_fence(__ATOMIC_RELEASE, "agent"); // one wbl2 for this XCD's L2
      unsigned b2 = __hip_atomic_fetch_add(gcnt, 1u, __ATOMIC_RELAXED, __HIP_MEMORY_SCOPE_AGENT);
      if ((b2 & 7u) == 7u)
        __hip_atomic_fetch_add(gen, 1u, __ATOMIC_RELAXED, __HIP_MEMORY_SCOPE_AGENT);
    }
    while (__hip_atomic_load(gen, __ATOMIC_RELAXED, __HIP_MEMORY_SCOPE_AGENT) == g)
      __builtin_amdgcn_s_sleep(4);
    __builtin_amdgcn_fence(__ATOMIC_ACQUIRE, "agent"); // per-CU L1 (+L2) invalidate
  }
  __syncthreads();
}

// ---------------- prep: temb, offs, rope tables ----------------
__global__ void k_prep(const int* __restrict__ mask, const float* __restrict__ ts,
                       float* __restrict__ temb, int* __restrict__ offs,
                       float* __restrict__ ropec, float* __restrict__ ropes)
{
  int t = threadIdx.x;
  {
    int b = t >> 5, l = t & 31;
    const int* mp = mask + b * PFXN;
    int s = 0;
    for (int k = l; k < PFXN; k += 32) s += (mp[k] != 0);
    #pragma unroll
    for (int off = 16; off >= 1; off >>= 1) s += __shfl_xor(s, off);
    if (l == 0) offs[b] = s;
  }
  for (int i = t; i < BATCH * 512; i += 256){
    int b = i >> 9, j = i & 511;
    float frac = (float)j * (1.0f / 511.0f);
    float period = 0.004f * __expf(frac * 6.907755278982137f);
    float arg = (6.283185307179586f / period) * ts[b];
    float s, c; sincosf(arg, &s, &c);
    temb[b * HIDN + j] = s;
    temb[b * HIDN + 512 + j] = c;
  }
  __syncthreads();
  for (int i = t; i < BATCH * AHOR * 128; i += 256){
    int d = i & 127, bt = i >> 7, b = bt / AHOR, tt = bt % AHOR;
    float inv = __expf(-((float)d * (1.f / 128.f)) * 9.210340371976184f);
    float arg = (float)(offs[b] + tt) * inv;
    float s, c; sincosf(arg, &s, &c);
    ropec[i] = c; ropes[i] = s;
  }
}

// ---------------- tiny M=8 GEMM (1024x1024) + silu ----------------
__global__ void k_tproj(const float* __restrict__ X, const float* __restrict__ W,
                        const float* __restrict__ bias, float* __restrict__ out)
{
  __shared__ float xs[BATCH * HIDN];
  __shared__ float red[BATCH][8][32];
  int t = threadIdx.x;
  for (int i = t; i < BATCH * HIDN; i += 256) xs[i] = X[i];
  __syncthreads();
  int c = t & 31, kp = t >> 5;
  int c0 = blockIdx.x * 32;
  float acc[BATCH];
  #pragma unroll
  for (int b = 0; b < BATCH; ++b) acc[b] = 0.f;
  for (int k = kp * 128; k < kp * 128 + 128; ++k){
    float w = W[(size_t)k * HIDN + c0 + c];
    #pragma unroll
    for (int b = 0; b < BATCH; ++b) acc[b] += xs[b * HIDN + k] * w;
  }
  #pragma unroll
  for (int b = 0; b < BATCH; ++b) red[b][kp][c] = acc[b];
  __syncthreads();
  int b2 = t >> 5, c2 = t & 31;
  float s = bias[c0 + c2];
  #pragma unroll
  for (int kp2 = 0; kp2 < 8; ++kp2) s += red[b2][kp2][c2];
  out[b2 * HIDN + c0 + c2] = siluf_(s);
}

// ---------------- ada partial: K-split x4, batched f4 loads ----------------
__global__ void k_ada_part(const float* __restrict__ cond, const float* __restrict__ A1,
                           const float* __restrict__ A2, const float* __restrict__ Af,
                           float* __restrict__ adap)
{
  __shared__ float cs[BATCH * 256];
  int t = threadIdx.x;
  int y = blockIdx.y, ks = blockIdx.z;
  int k0 = ks * 256;
  for (int i = t; i < BATCH * 256; i += 256){
    int b = i >> 8, kk = i & 255;
    cs[i] = cond[b * HIDN + k0 + kk];
  }
  __syncthreads();
  const float* A = (y < NLAY) ? (A1 + (size_t)y * HIDN * 3072)
                  : (y < 2 * NLAY) ? (A2 + (size_t)(y - NLAY) * HIDN * 3072) : Af;
  int n = (blockIdx.x * 256 + t) * 4;
  f4 acc[BATCH];
  #pragma unroll
  for (int b = 0; b < BATCH; ++b) acc[b] = (f4){0.f,0.f,0.f,0.f};
  const float* ap = A + (size_t)k0 * 3072 + n;
  for (int kk = 0; kk < 256; kk += 8){
    f4 av[8];
    #pragma unroll
    for (int j = 0; j < 8; ++j) av[j] = *(const f4*)(ap + (size_t)(kk + j) * 3072);
    #pragma unroll
    for (int j = 0; j < 8; ++j){
      #pragma unroll
      for (int b = 0; b < BATCH; ++b) acc[b] += av[j] * cs[b * 256 + kk + j];
    }
  }
  int comp = n >> 10, nn = n & 1023;
  float* o = adap + (size_t)ks * ADASL + ((size_t)y * 3 + comp) * BATCH * HIDN + nn;
  #pragma unroll
  for (int b = 0; b < BATCH; ++b) *(f4*)(o + b * HIDN) = acc[b];
}

__global__ void k_ada_red(const float* __restrict__ adap, float* __restrict__ ada)
{
  size_t i = ((size_t)blockIdx.x * 256 + threadIdx.x) * 8;
  f4 a0 = {0,0,0,0}, a1 = {0,0,0,0};
  #pragma unroll
  for (int ks = 0; ks < 4; ++ks){
    const float* p = adap + (size_t)ks * ADASL + i;
    a0 += *(const f4*)p;
    a1 += *(const f4*)(p + 4);
  }
  *(f4*)(ada + i) = a0;
  *(f4*)(ada + i + 4) = a1;
}

// ---------------- h0 = x_t @ W_act_in + b ----------------
__global__ void k_hin(const float* __restrict__ xt, const float* __restrict__ W,
                      const float* __restrict__ bias, float* __restrict__ h)
{
  int r = blockIdx.x;
  int t = threadIdx.x; int c0 = t * 4;
  __shared__ float xs[ADIMN];
  if (t < ADIMN) xs[t] = xt[r * ADIMN + t];
  __syncthreads();
  float a0 = bias[c0], a1 = bias[c0+1], a2 = bias[c0+2], a3 = bias[c0+3];
  for (int k = 0; k < ADIMN; ++k){
    float x = xs[k];
    const float* wp = W + k * HIDN + c0;
    a0 += x * wp[0]; a1 += x * wp[1]; a2 += x * wp[2]; a3 += x * wp[3];
  }
  float* hp = h + (size_t)r * HIDN + c0;
  hp[0] = a0; hp[1] = a1; hp[2] = a2; hp[3] = a3;
}

// ---------------- standalone RMS+AdaNorm (prologue only) ----------------
__global__ void k_resnorm0(const float* __restrict__ base, const float* __restrict__ sc,
                           const float* __restrict__ sh, u16* __restrict__ fragA)
{
  __shared__ float redl[4];
  int t = threadIdx.x;
  int c = t * 4;
  for (int i = 0; i < 4; ++i){
    int r = blockIdx.x * 4 + i;
    bool live = (r < MR);
    float4 v = {0.f,0.f,0.f,0.f};
    int b = live ? (r / AHOR) : 0;
    if (live) v = *(const float4*)(base + (size_t)r * HIDN + c);
    float ss = v.x*v.x + v.y*v.y + v.z*v.z + v.w*v.w;
    #pragma unroll
    for (int off = 1; off < 64; off <<= 1) ss += __shfl_xor(ss, off);
    if ((t & 63) == 0) redl[t >> 6] = ss;
    __syncthreads();
    float tot = redl[0] + redl[1] + redl[2] + redl[3];
    __syncthreads();
    u16* dst = fragA + ((size_t)(c >> 3)) * MP * 8 + (size_t)r * 8 + (c & 7);
    ushort4 ov;
    if (live){
      float rstd = rsqrtf(tot * (1.0f / HIDN) + EPSV);
      const float4 scp = *(const float4*)(sc + b * HIDN + c);
      const float4 shp = *(const float4*)(sh + b * HIDN + c);
      ov.x = f2bf(v.x * rstd * (1.f + scp.x) + shp.x);
      ov.y = f2bf(v.y * rstd * (1.f + scp.y) + shp.y);
      ov.z = f2bf(v.z * rstd * (1.f + scp.z) + shp.z);
      ov.w = f2bf(v.w * rstd * (1.f + scp.w) + shp.w);
    } else {
      ov.x = ov.y = ov.z = ov.w = 0;
    }
    *(ushort4*)dst = ov;
  }
}

// ---------------- GEMM core 64-col: dbuf LDS, depth-2 W prefetch, dbuf A prefetch ----------------
template<int NOUTER>
static __device__ __forceinline__ void gemm_core64(
    const u16* __restrict__ fa,
    const float* __restrict__ Wa, int cb0,
    const float* __restrict__ Wb, int cb1,
    int wN, int kc0, u16* lds, f4 acc[4][4])
{
  const int tid = threadIdx.x;
  const int lane = tid & 63, wave = tid >> 6;
  const int l15 = lane & 15, g = lane >> 4;
  const int wrow = wave * 64;
  const int sn = tid & 63, skb = (tid >> 6) * 8;
  const float* wbase = (sn < 32) ? (Wa + cb0 + sn) : (Wb + cb1 + (sn - 32));
  const size_t krow0 = (size_t)kc0 * 8 + skb;
  float pre[2][8];
  bh8 ab[2][2][4];
  #pragma unroll
  for (int j = 0; j < 8; ++j) pre[0][j] = wbase[(krow0 + j) * wN];
  #pragma unroll
  for (int kk = 0; kk < 2; ++kk){
    const u16* ap = fa + ((size_t)(kc0 + kk * 4 + g) * MP + wrow + l15) * 8;
    #pragma unroll
    for (int mf = 0; mf < 4; ++mf) ab[0][kk][mf] = *(const bh8*)(ap + mf * 128);
  }
  if (NOUTER > 1){
    #pragma unroll
    for (int j = 0; j < 8; ++j) pre[1][j] = wbase[(krow0 + 64 + j) * wN];
  }
  { u32* dst = (u32*)(lds + sn * 88 + skb);
    dst[0] = pack2(pre[0][0], pre[0][1]); dst[1] = pack2(pre[0][2], pre[0][3]);
    dst[2] = pack2(pre[0][4], pre[0][5]); dst[3] = pack2(pre[0][6], pre[0][7]); }
  __syncthreads();
  #pragma unroll
  for (int ko = 0; ko < NOUTER; ++ko){
    u16* ldsr = lds + (ko & 1) * (64 * 88);
    if (ko + 1 < NOUTER){ // A(ko+1) issued early, consumed next iter
      #pragma unroll
      for (int kk = 0; kk < 2; ++kk){
        const u16* ap = fa + ((size_t)(kc0 + (ko + 1) * 8 + kk * 4 + g) * MP + wrow + l15) * 8;
        #pragma unroll
        for (int mf = 0; mf < 4; ++mf) ab[(ko + 1) & 1][kk][mf] = *(const bh8*)(ap + mf * 128);
      }
    }
    if (ko + 2 < NOUTER){
      #pragma unroll
      for (int j = 0; j < 8; ++j) pre[ko & 1][j] = wbase[(krow0 + (size_t)(ko + 2) * 64 + j) * wN];
    }
    #pragma unroll
    for (int kk = 0; kk < 2; ++kk){
      bh8 bb[4];
      #pragma unroll
      for (int nf = 0; nf < 4; ++nf) bb[nf] = *(const bh8*)(ldsr + (nf * 16 + l15) * 88 + kk * 32 + g * 8);
      #pragma unroll
      for (int mf = 0; mf < 4; ++mf)
        #pragma unroll
        for (int nf = 0; nf < 4; ++nf)
          acc[mf][nf] = MFMA(ab[ko & 1][kk][mf], bb[nf], acc[mf][nf]);
    }
    if (ko + 1 < NOUTER){
      u16* ldsw = lds + ((ko + 1) & 1) * (64 * 88);
      u32* dst = (u32*)(ldsw + sn * 88 + skb);
      const float* p = pre[(ko + 1) & 1];
      dst[0] = pack2(p[0], p[1]); dst[1] = pack2(p[2], p[3]);
      dst[2] = pack2(p[4], p[5]); dst[3] = pack2(p[6], p[7]);
      __syncthreads();
    }
  }
}

// ---------------- GEMM core 32-col wide-K: 128 k/iter, dbuf, hoisted A ----------------
template<int NOUTER>
static __device__ __forceinline__ void gemm_core32w(
    const u16* __restrict__ fa,
    const float* __restrict__ Wa, int cb0,
    const float* __restrict__ Wb, int cb1,
    int wN, u16* lds, f4 acc[4][2])
{
  const int tid = threadIdx.x;
  const int lane = tid & 63, wave = tid >> 6;
  const int l15 = lane & 15, g = lane >> 4;
  const int wrow = wave * 64;
  const int sc = tid & 31, kq = tid >> 5;
  const int kb = kq * 8;
  const float* wbase = (sc < 16) ? (Wa + cb0 + sc) : (Wb + cb1 + (sc - 16));
  float pre[2][8];
  #pragma unroll
  for (int j = 0; j < 8; ++j) pre[0][j] = wbase[(size_t)(kb + j) * wN];
  if (NOUTER > 1){
    #pragma unroll
    for (int j = 0; j < 8; ++j) pre[1][j] = wbase[(size_t)(128 + kb + j) * wN];
  }
  { u32* dst = (u32*)(lds + sc * 136 + kb);
    dst[0] = pack2(pre[0][0], pre[0][1]); dst[1] = pack2(pre[0][2], pre[0][3]);
    dst[2] = pack2(pre[0][4], pre[0][5]); dst[3] = pack2(pre[0][6], pre[0][7]); }
  __syncthreads();
  #pragma unroll
  for (int ko = 0; ko < NOUTER; ++ko){
    u16* ldsr = lds + (ko & 1) * (32 * 136);
    bh8 a01[2][4], a23[2][4];
    #pragma unroll
    for (int kk = 0; kk < 2; ++kk){
      const u16* ap = fa + ((size_t)(ko * 16 + kk * 4 + g) * MP + wrow + l15) * 8;
      #pragma unroll
      for (int mf = 0; mf < 4; ++mf) a01[kk][mf] = *(const bh8*)(ap + mf * 128);
    }
    if (ko + 2 < NOUTER){
      #pragma unroll
      for (int j = 0; j < 8; ++j) pre[ko & 1][j] = wbase[(size_t)((ko + 2) * 128 + kb + j) * wN];
    }
    #pragma unroll
    for (int kk = 2; kk < 4; ++kk){ // hoisted: in flight during first MFMA cluster
      const u16* ap = fa + ((size_t)(ko * 16 + kk * 4 + g) * MP + wrow + l15) * 8;
      #pragma unroll
      for (int mf = 0; mf < 4; ++mf) a23[kk - 2][mf] = *(const bh8*)(ap + mf * 128);
    }
    #pragma unroll
    for (int kk = 0; kk < 2; ++kk){
      bh8 bb[2];
      #pragma unroll
      for (int nf = 0; nf < 2; ++nf) bb[nf] = *(const bh8*)(ldsr + (nf * 16 + l15) * 136 + kk * 32 + g * 8);
      #pragma unroll
      for (int mf = 0; mf < 4; ++mf){
        acc[mf][0] = MFMA(a01[kk][mf], bb[0], acc[mf][0]);
        acc[mf][1] = MFMA(a01[kk][mf], bb[1], acc[mf][1]);
      }
    }
    #pragma unroll
    for (int kk = 2; kk < 4; ++kk){
      bh8 bb[2];
      #pragma unroll
      for (int nf = 0; nf < 2; ++nf) bb[nf] = *(const bh8*)(ldsr + (nf * 16 + l15) * 136 + kk * 32 + g * 8);
      #pragma unroll
      for (int mf = 0; mf < 4; ++mf){
        acc[mf][0] = MFMA(a23[kk - 2][mf], bb[0], acc[mf][0]);
        acc[mf][1] = MFMA(a23[kk - 2][mf], bb[1], acc[mf][1]);
      }
    }
    if (ko + 1 < NOUTER){
      u16* ldsw = lds + ((ko + 1) & 1) * (32 * 136);
      u32* dst = (u32*)(ldsw + sc * 136 + kb);
      const float* p = pre[(ko + 1) & 1];
      dst[0] = pack2(p[0], p[1]); dst[1] = pack2(p[2], p[3]);
      dst[2] = pack2(p[4], p[5]); dst[3] = pack2(p[6], p[7]);
      __syncthreads();
    }
  }
}

// ================= mega-kernel phase bodies (512 threads each) =================

// fused QKV GEMM (K=1024 full) + RoPE epilogue -> qf/kss/vss. 40 tasks.
static __device__ __forceinline__ void ph_qkvrope(int bx,
    const u16* n1, const float* Wq, const float* Wk, const float* Wv,
    const float* ropec, const float* ropes,
    u16* qf, u16* ks, u16* vs, u16* lds)
{
  const float* Wa; int cb0, cb1, wN, head = 0, d0 = 0, type;
  if (bx < 32){ type = 0; head = bx >> 2; d0 = (bx & 3) * 32; Wa = Wq; wN = NHEAD * HD; cb0 = head * HD + d0; cb1 = cb0 + 128; }
  else if (bx < 36){ type = 1; d0 = (bx - 32) * 32; Wa = Wk; wN = HD; cb0 = d0; cb1 = d0 + 128; }
  else { type = 2; d0 = (bx - 36) * 64; Wa = Wv; wN = HD; cb0 = d0; cb1 = cb0 + 32; }
  f4 acc[4][4];
  #pragma unroll
  for (int i = 0; i < 4; ++i)
    #pragma unroll
    for (int j = 0; j < 4; ++j) acc[i][j] = (f4){0.f, 0.f, 0.f, 0.f};
  gemm_core64<16>(n1, Wa, cb0, Wa, cb1, wN, 0, lds, acc);
  int tid = threadIdx.x, lane = tid & 63, wave = tid >> 6, l15 = lane & 15, g = lane >> 4;
  int wrow = wave * 64;
  #pragma unroll
  for (int mf = 0; mf < 4; ++mf)
    #pragma unroll
    for (int r = 0; r < 4; ++r){
      int row = wrow + mf * 16 + 4 * g + r;
      if (row >= MR) continue;
      int b = row / AHOR, tt = row - b * AHOR;
      if (type == 2){
        #pragma unroll
        for (int nf = 0; nf < 4; ++nf){
          int d = d0 + nf * 16 + l15;
          vs[((size_t)(b * AHOR + tt)) * HD + d] = f2bf(acc[mf][nf][r]);
        }
      } else {
        #pragma unroll
        for (int nf = 0; nf < 2; ++nf){
          int dA = d0 + nf * 16 + l15;
          float cz = ropec[(size_t)(b * AHOR + tt) * 128 + dA];
          float sz = ropes[(size_t)(b * AHOR + tt) * 128 + dA];
          float a = acc[mf][nf][r], bv = acc[mf][nf + 2][r];
          float oA = a * cz - bv * sz;
          float oB = bv * cz + a * sz;
          if (type == 0){
            oA *= QSCALE; oB *= QSCALE;
            int rowp = head * AHOR + tt;
            int dB = dA + 128;
            qf[((size_t)(b * 32 + (dA >> 3))) * MP * 8 + (size_t)rowp * 8 + (dA & 7)] = f2bf(oA);
            qf[((size_t)(b * 32 + (dB >> 3))) * MP * 8 + (size_t)rowp * 8 + (dB & 7)] = f2bf(oB);
          } else {
            size_t kb = ((size_t)(b * AHOR + tt)) * HD;
            ks[kb + dA] = f2bf(oA);
            ks[kb + dA + 128] = f2bf(oB);
          }
        }
      }
    }
}

static __device__ __forceinline__ void ph_attn(int task, int layer,
    const u16* qf, const u16* kss, const u16* vss,
    const float* pk, const float* pv, const int* mask,
    u16* opart, float* mrow, float* lrow, u16* kv, u16* plds)
{
  __syncthreads();
  int s = task % NSTR, b = task / NSTR;
  int tid = threadIdx.x, lane = tid & 63, wave = tid >> 6, l15 = lane & 15, g = lane >> 4;
  int wrow = wave * 64;
  int key = tid >> 3, dblk = (tid & 7) * 32;
  int kg = s * 64 + key;
  {
    u32* dst = (u32*)(kv + key * 264 + dblk);
    if (kg < PFXN){
      const float4* src = (const float4*)(pk + (((size_t)b * NLAY + layer) * PFXN + kg) * HD + dblk);
      #pragma unroll
      for (int j = 0; j < 8; ++j){ float4 v = src[j]; dst[2*j] = pack2(v.x, v.y); dst[2*j+1] = pack2(v.z, v.w); }
    } else if (kg < SEQN){
      const u32* src = (const u32*)(kss + ((size_t)b * AHOR + (kg - PFXN)) * HD + dblk);
      #pragma unroll
      for (int j = 0; j < 16; ++j) dst[j] = src[j];
    } else {
      #pragma unroll
      for (int j = 0; j < 16; ++j) dst[j] = 0;
    }
  }
  float vreg[32];
  if (kg < PFXN){
    const float4* src = (const float4*)(pv + (((size_t)b * NLAY + layer) * PFXN + kg) * HD + dblk);
    #pragma unroll
    for (int j = 0; j < 8; ++j){ float4 v = src[j]; vreg[4*j] = v.x; vreg[4*j+1] = v.y; vreg[4*j+2] = v.z; vreg[4*j+3] = v.w; }
  } else if (kg < SEQN){
    const u32* src = (const u32*)(vss + ((size_t)b * AHOR + (kg - PFXN)) * HD + dblk);
    #pragma unroll
    for (int j = 0; j < 16; ++j){ u32 u = src[j]; vreg[2*j] = bf2f((u16)(u & 0xFFFF)); vreg[2*j+1] = bf2f((u16)(u >> 16)); }
  } else {
    #pragma unroll
    for (int j = 0; j < 32; ++j) vreg[j] = 0.f;
  }
  bool valid[4];
  #pragma unroll
  for (int nf = 0; nf < 4; ++nf){
    int kgc = s * 64 + nf * 16 + l15;
    valid[nf] = (kgc < PFXN) ? (mask[b * PFXN + kgc] != 0) : (kgc < SEQN);
  }
  __syncthreads();
  f4 acc[4][4];
  #pragma unroll
  for (int i = 0; i < 4; ++i)
    #pragma unroll
    for (int j = 0; j < 4; ++j) acc[i][j] = (f4){0.f,0.f,0.f,0.f};
  const u16* qb = qf + (size_t)b * 32 * MP * 8;
  #pragma unroll
  for (int ko = 0; ko < 4; ++ko)
    #pragma unroll
    for (int kk = 0; kk < 2; ++kk){
      int kc = ko * 8 + kk * 4 + g;
      bh8 a[4], bb[4];
      const u16* ap = qb + ((size_t)kc * MP + wrow + l15) * 8;
      #pragma unroll
      for (int mf = 0; mf < 4; ++mf) a[mf] = *(const bh8*)(ap + mf * 128);
      #pragma unroll
      for (int nf = 0; nf < 4; ++nf) bb[nf] = *(const bh8*)(kv + (nf * 16 + l15) * 264 + ko * 64 + kk * 32 + g * 8);
      #pragma unroll
      for (int mf = 0; mf < 4; ++mf)
        #pragma unroll
        for (int nf = 0; nf < 4; ++nf) acc[mf][nf] = MFMA(a[mf], bb[nf], acc[mf][nf]);
    }
  #pragma unroll
  for (int nf = 0; nf < 4; ++nf) if (!valid[nf]){
    #pragma unroll
    for (int mf = 0; mf < 4; ++mf){
      acc[mf][nf][0] = NEGV; acc[mf][nf][1] = NEGV; acc[mf][nf][2] = NEGV; acc[mf][nf][3] = NEGV;
    }
  }
  #pragma unroll
  for (int mf = 0; mf < 4; ++mf)
    #pragma unroll
    for (int r = 0; r < 4; ++r){
      float m0 = fmaxf(fmaxf(acc[mf][0][r], acc[mf][1][r]), fmaxf(acc[mf][2][r], acc[mf][3][r]));
      #pragma unroll
      for (int off = 1; off < 16; off <<= 1) m0 = fmaxf(m0, __shfl_xor(m0, off));
      int row = wrow + mf * 16 + 4 * g + r;
      float sum = 0.f;
      #pragma unroll
      for (int nf = 0; nf < 4; ++nf){
        float p = __expf(acc[mf][nf][r] - m0);
        sum += p;
        plds[row * 72 + nf * 16 + l15] = f2bf(p);
      }
      #pragma unroll
      for (int off = 1; off < 16; off <<= 1) sum += __shfl_xor(sum, off);
      if (l15 == 0){
        mrow[((size_t)b * NSTR + s) * MP + row] = m0;
        lrow[((size_t)b * NSTR + s) * MP + row] = sum;
      }
    }
  __syncthreads();
  {
    #pragma unroll
    for (int j = 0; j < 32; ++j){
      int d = dblk + j;
      kv[d * 88 + ((d >> 5) & 3) * 8 + key] = f2bf(vreg[j]);
    }
  }
  __syncthreads();
  #pragma unroll
  for (int dc = 0; dc < 4; ++dc){
    f4 oc[4][4];
    #pragma unroll
    for (int i = 0; i < 4; ++i)
      #pragma unroll
      for (int j = 0; j < 4; ++j) oc[i][j] = (f4){0.f,0.f,0.f,0.f};
    #pragma unroll
    for (int kk = 0; kk < 2; ++kk){
      bh8 a[4], bb[4];
      #pragma unroll
      for (int mf = 0; mf < 4; ++mf) a[mf] = *(const bh8*)(plds + (wrow + mf * 16 + l15) * 72 + kk * 32 + g * 8);
      #pragma unroll
      for (int nf = 0; nf < 4; ++nf){
        int dcol = dc * 64 + nf * 16 + l15;
        bb[nf] = *(const bh8*)(kv + dcol * 88 + ((dcol >> 5) & 3) * 8 + kk * 32 + g * 8);
      }
      #pragma unroll
      for (int mf = 0; mf < 4; ++mf)
        #pragma unroll
        for (int nf = 0; nf < 4; ++nf) oc[mf][nf] = MFMA(a[mf], bb[nf], oc[mf][nf]);
    }
    #pragma unroll
    for (int mf = 0; mf < 4; ++mf)
      #pragma unroll
      for (int r = 0; r < 4; ++r){
        int row = wrow + mf * 16 + 4 * g + r;
        if (row < MR){
          #pragma unroll
          for (int nf = 0; nf < 4; ++nf){
            int d = dc * 64 + nf * 16 + l15;
            opart[(((size_t)b * NSTR + s) * MR + row) * HD + d] = f2bf(oc[mf][nf][r]);
          }
        }
      }
  }
}

static __device__ __forceinline__ void ph_comb(int task,
    const u16* opart, const float* mrow, const float* lrow, u16* ao)
{
  int rg = task % 25, b = task / 25;
  int tid = threadIdx.x;
  int d = tid & 255, half = tid >> 8;
  int r0 = rg * 16 + half * 8;
  for (int i = 0; i < 8; ++i){
    int row = r0 + i;
    float M = -3.0e38f;
    for (int s2 = 0; s2 < NSTR; ++s2) M = fmaxf(M, mrow[((size_t)b * NSTR + s2) * MP + row]);
    float L = 0.f, o = 0.f;
    for (int s2 = 0; s2 < NSTR; ++s2){
      float w = __expf(mrow[((size_t)b * NSTR + s2) * MP + row] - M);
      L += w * lrow[((size_t)b * NSTR + s2) * MP + row];
      o += w * bf2f(opart[(((size_t)b * NSTR + s2) * MR + row) * HD + d]);
    }
    float val = o / L;
    int h = row / AHOR, tt = row - h * AHOR;
    int col = h * HD + d;
    int rgl = b * AHOR + tt;
    ao[((size_t)(col >> 3)) * MP * 8 + (size_t)rgl * 8 + (col & 7)] = f2bf(val);
  }
}

template<int NOUTER>
static __device__ __forceinline__ void ph_gemm(int task,
    const u16* fa, const float* W, int wN, int kcPerSlice, u16* outp, u16* lds)
{
  int nx = task & 15, ksl = task >> 4;
  int n0 = nx * 64;
  f4 acc[4][4];
  #pragma unroll
  for (int i = 0; i < 4; ++i)
    #pragma unroll
    for (int j = 0; j < 4; ++j) acc[i][j] = (f4){0.f,0.f,0.f,0.f};
  gemm_core64<NOUTER>(fa, W, n0, W, n0 + 32, wN, ksl * kcPerSlice, lds, acc);
  int tid = threadIdx.x, lane = tid & 63, wave = tid >> 6, l15 = lane & 15, g = lane >> 4;
  int wrow = wave * 64;
  #pragma unroll
  for (int mf = 0; mf < 4; ++mf)
    #pragma unroll
    for (int r = 0; r < 4; ++r){
      int row = wrow + mf * 16 + 4 * g + r;
      #pragma unroll
      for (int nf = 0; nf < 4; ++nf)
        outp[((size_t)ksl * MP + row) * 1024 + n0 + nf * 16 + l15] = f2bf(acc[mf][nf][r]);
    }
}

static __device__ __forceinline__ void ph_mlpup(int task,
    const u16* n2, const float* Wg, const float* Wu, u16* mlpf, u16* lds)
{
  int n0 = task * 16;
  f4 acc[4][2];
  #pragma unroll
  for (int i = 0; i < 4; ++i)
    #pragma unroll
    for (int j = 0; j < 2; ++j) acc[i][j] = (f4){0.f,0.f,0.f,0.f};
  gemm_core32w<8>(n2, Wg, n0, Wu, n0, DMLP, lds, acc);
  int tid = threadIdx.x, lane = tid & 63, wave = tid >> 6, l15 = lane & 15, g = lane >> 4;
  int wrow = wave * 64;
  #pragma unroll
  for (int mf = 0; mf < 4; ++mf)
    #pragma unroll
    for (int r = 0; r < 4; ++r){
      int row = wrow + mf * 16 + 4 * g + r;
      int col = n0 + l15;
      float gg = acc[mf][0][r], uu = acc[mf][1][r];
      float act = geluf_(gg) * uu;
      mlpf[((size_t)(col >> 3)) * MP * 8 + (size_t)row * 8 + (col & 7)] = f2bf(act);
    }
}

static __device__ __forceinline__ void ph_resnorm(int task, int np,
    const float* base, const u16* parts, const float* gate, const float* sc,
    const float* sh, float* outres, u16* fragA, float* redl)
{
  int tid = threadIdx.x;
  int tl = tid & 255, sub = tid >> 8;
  int c = tl * 4;
  int wv = tid >> 6;
  for (int i = 0; i < 2; ++i){
    int r = task * 4 + sub * 2 + i;
    bool live = (r < MR);
    float4 v = {0.f,0.f,0.f,0.f};
    int b = live ? (r / AHOR) : 0;
    if (live){
      v = *(const float4*)(base + (size_t)r * HIDN + c);
      float s0 = 0, s1 = 0, s2 = 0, s3 = 0;
      #pragma unroll 4
      for (int p = 0; p < np; ++p){
        ushort4 u4 = *(const ushort4*)(parts + ((size_t)p * MP + r) * HIDN + c);
        s0 += bf2f(u4.x); s1 += bf2f(u4.y); s2 += bf2f(u4.z); s3 += bf2f(u4.w);
      }
      float4 gp = *(const float4*)(gate + b * HIDN + c);
      v.x += gp.x * s0; v.y += gp.y * s1; v.z += gp.z * s2; v.w += gp.w * s3;
      *(float4*)(outres + (size_t)r * HIDN + c) = v;
    }
    float ss = v.x*v.x + v.y*v.y + v.z*v.z + v.w*v.w;
    #pragma unroll
    for (int off = 1; off < 64; off <<= 1) ss += __shfl_xor(ss, off);
    if ((tid & 63) == 0) redl[wv] = ss;
    __syncthreads();
    float tot = redl[sub * 4] + redl[sub * 4 + 1] + redl[sub * 4 + 2] + redl[sub * 4 + 3];
    __syncthreads();
    u16* dst = fragA + ((size_t)(c >> 3)) * MP * 8 + (size_t)r * 8 + (c & 7);
    ushort4 ov;
    if (live){
      float rstd = rsqrtf(tot * (1.0f / HIDN) + EPSV);
      const float4 scp = *(const float4*)(sc + b * HIDN + c);
      const float4 shp = *(const float4*)(sh + b * HIDN + c);
      ov.x = f2bf(v.x * rstd * (1.f + scp.x) + shp.x);
      ov.y = f2bf(v.y * rstd * (1.f + scp.y) + shp.y);
      ov.z = f2bf(v.z * rstd * (1.f + scp.z) + shp.z);
      ov.w = f2bf(v.w * rstd * (1.f + scp.w) + shp.w);
    } else {
      ov.x = ov.y = ov.z = ov.w = 0;
    }
    *(ushort4*)dst = ov;
  }
}

// ================= the persistent 18-layer mega-kernel =================
__global__ __launch_bounds__(512, 2) void k_layers(
    const float* __restrict__ pk, const float* __restrict__ pv, const int* __restrict__ msk,
    const float* __restrict__ ropec, const float* __restrict__ ropes,
    const float* __restrict__ Wq, const float* __restrict__ Wk, const float* __restrict__ Wv,
    const float* __restrict__ Wo, const float* __restrict__ Wg, const float* __restrict__ Wu,
    const float* __restrict__ Wd, const float* __restrict__ ada,
    float* h, float* h1, u16* n1, u16* n2,
    u16* qf, u16* kss, u16* vss,
    u16* opart, float* mrow, float* lrow, u16* ao,
    u16* opp, u16* mlpf, u16* mdp, unsigned* bar)
{
  __shared__ u16 smem[256 * 88 + 512 * 72];
  __shared__ float redl[8];
  u16* kv = smem;
  u16* plds = smem + 256 * 88;
  const int bid = blockIdx.x, G = gridDim.x;
  const int xcc = xcc_id();

  for (int l = 0; l < NLAY; ++l){
    const float* Wq_l = Wq + (size_t)l * HIDN * NHEAD * HD;
    const float* Wk_l = Wk + (size_t)l * HIDN * HD;
    const float* Wv_l = Wv + (size_t)l * HIDN * HD;
    const float* Wo_l = Wo + (size_t)l * 2048 * 1024;
    const float* Wg_l = Wg + (size_t)l * HIDN * DMLP;
    const float* Wu_l = Wu + (size_t)l * HIDN * DMLP;
    const float* Wd_l = Wd + (size_t)l * DMLP * 1024;
    const float* g1  = ada + ((size_t)l * 3 + 2) * BATCH * HIDN;
    const float* sc2 = ada + ((size_t)(NLAY + l) * 3 + 0) * BATCH * HIDN;
    const float* sh2 = ada + ((size_t)(NLAY + l) * 3 + 1) * BATCH * HIDN;
    const float* g2  = ada + ((size_t)(NLAY + l) * 3 + 2) * BATCH * HIDN;
    int ny = (l < NLAY - 1) ? (l + 1) : 36;
    const float* nsc = ada + ((size_t)ny * 3 + 0) * BATCH * HIDN;
    const float* nsh = ada + ((size_t)ny * 3 + 1) * BATCH * HIDN;

    for (int t = bid; t < 40; t += G) ph_qkvrope(t, n1, Wq_l, Wk_l, Wv_l, ropec, ropes, qf, kss, vss, smem);
    gsync(bar, xcc);
    for (int t = bid; t < NSTR * BATCH; t += G) ph_attn(t, l, qf, kss, vss, pk, pv, msk, opart, mrow, lrow, kv, plds);
    gsync(bar, xcc);
    for (int t = bid; t < 200; t += G) ph_comb(t, opart, mrow, lrow, ao);
    gsync(bar, xcc);
    for (int t = bid; t < 128; t += G) ph_gemm<4>(t, ao, Wo_l, 1024, 32, opp, smem);
    gsync(bar, xcc);
    for (int t = bid; t < 128; t += G) ph_resnorm(t, 8, h, opp, g1, sc2, sh2, h1, n2, redl);
    gsync(bar, xcc);
    for (int t = bid; t < 256; t += G) ph_mlpup(t, n2, Wg_l, Wu_l, mlpf, smem);
    gsync(bar, xcc);
    for (int t = bid; t < 128; t += G) ph_gemm<8>(t, mlpf, Wd_l, 1024, 64, mdp, smem);
    gsync(bar, xcc);
    for (int t = bid; t < 128; t += G) ph_resnorm(t, 8, h1, mdp, g2, nsc, nsh, h, n1, redl);
    if (l < NLAY - 1) gsync(bar, xcc);
  }
}

// ---------------- final: out = nf @ W_act_out + b ----------------
__global__ void k_out(const u16* __restrict__ nfr, const float* __restrict__ W,
                      const float* __restrict__ bias, float* __restrict__ out)
{
  int t = threadIdx.x;
  int row = blockIdx.x * 8 + (t >> 5);
  int c = t & 31;
  float acc = bias[c];
  for (int k = 0; k < HIDN; ++k)
    acc += bf2f(nfr[((size_t)(k >> 3)) * MP * 8 + (size_t)row * 8 + (k & 7)]) * W[k * ADIMN + c];
  out[row * ADIMN + c] = acc;
}

extern "C" void kernel_launch(void* const* d_in, const int* in_sizes, int n_in,
                              void* d_out, int out_size, void* d_ws, size_t ws_size,
                              hipStream_t stream)
{
  const float* pk  = (const float*)d_in[0];
  const float* pv  = (const float*)d_in[1];
  const int*   msk = (const int*)d_in[2];
  const float* xt  = (const float*)d_in[3];
  const float* ts  = (const float*)d_in[4];
  const float* Wq  = (const float*)d_in[5];
  const float* Wk  = (const float*)d_in[6];
  const float* Wv  = (const float*)d_in[7];
  const float* Wo  = (const float*)d_in[8];
  const float* Wg  = (const float*)d_in[9];
  const float* Wu  = (const float*)d_in[10];
  const float* Wd  = (const float*)d_in[11];
  const float* A1  = (const float*)d_in[12];
  const float* A2  = (const float*)d_in[13];
  const float* Af  = (const float*)d_in[14];
  const float* Wai = (const float*)d_in[15];
  const float* bai = (const float*)d_in[16];
  const float* Wao = (const float*)d_in[17];
  const float* bao = (const float*)d_in[18];
  const float* Wti = (const float*)d_in[19];
  const float* bti = (const float*)d_in[20];
  const float* Wto = (const float*)d_in[21];
  const float* bto = (const float*)d_in[22];

  char* w = (char*)d_ws;
  size_t off = 0;
  auto alloc = [&](size_t bytes) -> char* {
    char* p = w + off; off += (bytes + 255) & ~(size_t)255; return p;
  };
  float* temb  = (float*)alloc((size_t)BATCH * HIDN * 4);
  float* ttmp  = (float*)alloc((size_t)BATCH * HIDN * 4);
  float* cond  = (float*)alloc((size_t)BATCH * HIDN * 4);
  int*   offs  = (int*)alloc(BATCH * 4);
  float* ropec = (float*)alloc((size_t)BATCH * AHOR * 128 * 4);
  float* ropes = (float*)alloc((size_t)BATCH * AHOR * 128 * 4);
  float* ada   = (float*)alloc(ADASL * 4);
  float* adap  = (float*)alloc(4 * ADASL * 4);
  float* h     = (float*)alloc((size_t)MR * HIDN * 4);
  float* h1    = (float*)alloc((size_t)MR * HIDN * 4);
  u16*   n1    = (u16*)alloc((size_t)128 * MP * 8 * 2);
  u16*   n2    = (u16*)alloc((size_t)128 * MP * 8 * 2);
  u16*   qf    = (u16*)alloc((size_t)BATCH * 32 * MP * 8 * 2);
  u16*   kss   = (u16*)alloc((size_t)BATCH * AHOR * HD * 2);
  u16*   vss   = (u16*)alloc((size_t)BATCH * AHOR * HD * 2);
  u16*   opart = (u16*)alloc((size_t)BATCH * NSTR * MR * HD * 2);
  float* mrow  = (float*)alloc((size_t)BATCH * NSTR * MP * 4);
  float* lrow  = (float*)alloc((size_t)BATCH * NSTR * MP * 4);
  u16*   ao    = (u16*)alloc((size_t)256 * MP * 8 * 2);
  u16*   opp   = (u16*)alloc((size_t)8 * MP * 1024 * 2);
  u16*   mlpf  = (u16*)alloc((size_t)512 * MP * 8 * 2);
  u16*   mdp   = (u16*)alloc((size_t)8 * MP * 1024 * 2);
  unsigned* bar = (unsigned*)alloc(2048);
  if (off > ws_size) return;

  hipMemsetAsync(bar, 0, 2048, stream);

  k_prep<<<1, 256, 0, stream>>>(msk, ts, temb, offs, ropec, ropes);
  k_tproj<<<32, 256, 0, stream>>>(temb, Wti, bti, ttmp);
  k_tproj<<<32, 256, 0, stream>>>(ttmp, Wto, bto, cond);
  k_ada_part<<<dim3(3, 37, 4), 256, 0, stream>>>(cond, A1, A2, Af, adap);
  k_ada_red<<<444, 256, 0, stream>>>(adap, ada);
  k_hin<<<MR, 256, 0, stream>>>(xt, Wai, bai, h);
  k_resnorm0<<<128, 256, 0, stream>>>(h, ada + 0, ada + (size_t)1 * BATCH * HIDN, n1);

  k_layers<<<NBLK, 512, 0, stream>>>(pk, pv, msk, ropec, ropes,
                                     Wq, Wk, Wv, Wo, Wg, Wu, Wd, ada,
                                     h, h1, n1, n2, qf, kss, vss,
                                     opart, mrow, lrow, ao, opp, mlpf, mdp, bar);

  k_out<<<50, 256, 0, stream>>>(n1, Wao, bao, (float*)d_out);
}